// Round 2
// baseline (8599.820 us; speedup 1.0000x reference)
//
#include <hip/hip_runtime.h>
#include <hip/hip_bf16.h>

static constexpr int kB = 4;
static constexpr int kT = 1024;
static constexpr int kIn = 172;
static constexpr int kD = 512;
static constexpr int kH = 8;
static constexpr int kHD = 64;
static constexpr int kFF = 2048;
static constexpr int kNCLS = 1296;
static constexpr float kEps = 1e-5f;

#define GBM 64
#define GBN 64
#define GBK 16
#define LDST 68   // row stride: 68 floats = 272 B = 17*16 B, keeps float4 alignment

// ---------- generic GEMM: C[m,n] = sum_k A[m,k]*W[n,k] + bias[n] (+relu)(+resid) ----------
__global__ __launch_bounds__(256) void gemm_kernel(
    const float* __restrict__ A, const float* __restrict__ W,
    const float* __restrict__ bias, const float* __restrict__ resid,
    float* __restrict__ C, int M, int N, int K, int doRelu)
{
  __shared__ __align__(16) float As[GBK][LDST];
  __shared__ __align__(16) float Ws[GBK][LDST];
  const int tid = threadIdx.x;
  const int bm = blockIdx.y * GBM;
  const int bn = blockIdx.x * GBN;
  const int tx = tid & 15, ty = tid >> 4;
  const int li = tid >> 2;          // 0..63 : row (A) / col (W) within tile
  const int lk = (tid & 3) << 2;    // 0,4,8,12 : k offset

  float acc[4][4];
#pragma unroll
  for (int i = 0; i < 4; ++i)
#pragma unroll
    for (int j = 0; j < 4; ++j) acc[i][j] = 0.f;

  for (int k0 = 0; k0 < K; k0 += GBK) {
    float4 av = make_float4(0.f, 0.f, 0.f, 0.f);
    float4 wv = make_float4(0.f, 0.f, 0.f, 0.f);
    {
      const int m = bm + li;
      if (m < M) {
        if (k0 + lk + 4 <= K) {
          av = *(const float4*)&A[(size_t)m * K + k0 + lk];
        } else {
          float t4[4] = {0.f, 0.f, 0.f, 0.f};
          for (int c = 0; c < 4; ++c) { int k = k0 + lk + c; if (k < K) t4[c] = A[(size_t)m * K + k]; }
          av = make_float4(t4[0], t4[1], t4[2], t4[3]);
        }
      }
      const int n = bn + li;
      if (n < N) {
        if (k0 + lk + 4 <= K) {
          wv = *(const float4*)&W[(size_t)n * K + k0 + lk];
        } else {
          float t4[4] = {0.f, 0.f, 0.f, 0.f};
          for (int c = 0; c < 4; ++c) { int k = k0 + lk + c; if (k < K) t4[c] = W[(size_t)n * K + k]; }
          wv = make_float4(t4[0], t4[1], t4[2], t4[3]);
        }
      }
    }
    __syncthreads();   // protect LDS from previous iteration's readers
    As[lk + 0][li] = av.x; As[lk + 1][li] = av.y; As[lk + 2][li] = av.z; As[lk + 3][li] = av.w;
    Ws[lk + 0][li] = wv.x; Ws[lk + 1][li] = wv.y; Ws[lk + 2][li] = wv.z; Ws[lk + 3][li] = wv.w;
    __syncthreads();
#pragma unroll
    for (int kk = 0; kk < GBK; ++kk) {
      const float4 a4 = *(const float4*)&As[kk][ty << 2];
      const float4 b4 = *(const float4*)&Ws[kk][tx << 2];
      const float a[4] = {a4.x, a4.y, a4.z, a4.w};
      const float b[4] = {b4.x, b4.y, b4.z, b4.w};
#pragma unroll
      for (int i = 0; i < 4; ++i)
#pragma unroll
        for (int j = 0; j < 4; ++j) acc[i][j] = fmaf(a[i], b[j], acc[i][j]);
    }
  }

#pragma unroll
  for (int i = 0; i < 4; ++i) {
    const int m = bm + (ty << 2) + i;
    if (m >= M) continue;
#pragma unroll
    for (int j = 0; j < 4; ++j) {
      const int n = bn + (tx << 2) + j;
      if (n >= N) continue;
      float v = acc[i][j] + bias[n];
      if (doRelu) v = fmaxf(v, 0.f);
      if (resid) v += resid[(size_t)m * N + n];
      C[(size_t)m * N + n] = v;
    }
  }
}

// ---------- LayerNorm (in-place), one block per row of 512 ----------
__global__ __launch_bounds__(256) void ln_kernel(
    float* __restrict__ X, const float* __restrict__ g, const float* __restrict__ bta)
{
  const int row = blockIdx.x;
  const int tid = threadIdx.x;
  float* xr = X + (size_t)row * kD;
  const float x0 = xr[tid];
  const float x1 = xr[tid + 256];
  float s = x0 + x1;
  float q = x0 * x0 + x1 * x1;
#pragma unroll
  for (int off = 32; off > 0; off >>= 1) {
    s += __shfl_down(s, off);
    q += __shfl_down(q, off);
  }
  __shared__ float ss[4], qq[4];
  const int w = tid >> 6;
  if ((tid & 63) == 0) { ss[w] = s; qq[w] = q; }
  __syncthreads();
  const float S = ss[0] + ss[1] + ss[2] + ss[3];
  const float Q = qq[0] + qq[1] + qq[2] + qq[3];
  const float mean = S * (1.f / kD);
  const float var = Q * (1.f / kD) - mean * mean;
  const float inv = rsqrtf(var + kEps);
  xr[tid]       = (x0 - mean) * inv * g[tid] + bta[tid];
  xr[tid + 256] = (x1 - mean) * inv * g[tid + 256] + bta[tid + 256];
}

// ---------- flash-style attention, f32 ----------
// grid: (T/16, H, B), block 256 = 4 waves; wave w handles 4 q-rows.
__global__ __launch_bounds__(256) void attn_kernel(
    const float* __restrict__ qkv, float* __restrict__ O)
{
  const int b = blockIdx.z, h = blockIdx.y;
  const int q0 = blockIdx.x << 4;
  const int tid = threadIdx.x;
  const int w = tid >> 6, lane = tid & 63;
  __shared__ float qs[16][kHD];
  __shared__ float Ks[64][kHD + 1];   // +1 pad: (row+d)%32 banks -> 2-way only (free)
  __shared__ float Vs[64][kHD + 1];
  {
    const int r = tid >> 4, dc = (tid & 15) << 2;
    const float4 v = *(const float4*)&qkv[((size_t)(b * kT + q0 + r)) * (3 * kD) + h * kHD + dc];
    qs[r][dc] = v.x; qs[r][dc + 1] = v.y; qs[r][dc + 2] = v.z; qs[r][dc + 3] = v.w;
  }
  float m_[4], l_[4], o_[4];
#pragma unroll
  for (int rr = 0; rr < 4; ++rr) { m_[rr] = -1e30f; l_[rr] = 0.f; o_[rr] = 0.f; }

  for (int kt = 0; kt < kT / 64; ++kt) {
    __syncthreads();
    {
      const int r = tid >> 2, dc = (tid & 3) << 4;
      const float* kb = &qkv[((size_t)(b * kT + (kt << 6) + r)) * (3 * kD) + kD + h * kHD + dc];
#pragma unroll
      for (int c = 0; c < 4; ++c) {
        const float4 kv = *(const float4*)&kb[c * 4];
        Ks[r][dc + c * 4 + 0] = kv.x; Ks[r][dc + c * 4 + 1] = kv.y;
        Ks[r][dc + c * 4 + 2] = kv.z; Ks[r][dc + c * 4 + 3] = kv.w;
        const float4 vv = *(const float4*)&kb[kD + c * 4];
        Vs[r][dc + c * 4 + 0] = vv.x; Vs[r][dc + c * 4 + 1] = vv.y;
        Vs[r][dc + c * 4 + 2] = vv.z; Vs[r][dc + c * 4 + 3] = vv.w;
      }
    }
    __syncthreads();
#pragma unroll
    for (int rr = 0; rr < 4; ++rr) {
      const int r = (w << 2) + rr;
      float s = 0.f;
#pragma unroll
      for (int d = 0; d < kHD; ++d) s = fmaf(qs[r][d], Ks[lane][d], s);
      s *= 0.125f;  // 1/sqrt(64)
      float mx = s;
#pragma unroll
      for (int off = 32; off > 0; off >>= 1) mx = fmaxf(mx, __shfl_xor(mx, off));
      const float mnew = fmaxf(m_[rr], mx);
      const float p = expf(s - mnew);
      float ps = p;
#pragma unroll
      for (int off = 32; off > 0; off >>= 1) ps += __shfl_xor(ps, off);
      const float alpha = expf(m_[rr] - mnew);   // 0 on first tile (m_=-1e30)
      l_[rr] = l_[rr] * alpha + ps;
      m_[rr] = mnew;
      float o = o_[rr] * alpha;
#pragma unroll
      for (int j = 0; j < 64; ++j) o = fmaf(__shfl(p, j), Vs[j][lane], o);
      o_[rr] = o;
    }
  }
#pragma unroll
  for (int rr = 0; rr < 4; ++rr) {
    const int qrow = q0 + (w << 2) + rr;
    O[((size_t)(b * kT + qrow)) * kD + h * kHD + lane] = o_[rr] / l_[rr];
  }
}

// ---------- positional encoding add ----------
__global__ __launch_bounds__(256) void posenc_kernel(float* __restrict__ X)
{
  const int bt = blockIdx.x;
  const int t = bt & (kT - 1);
  float* row = X + (size_t)bt * kD;
#pragma unroll
  for (int p = 0; p < 2; ++p) {
    const int d = threadIdx.x + p * 256;
    const int j = d >> 1;
    const float inv = expf(-(float)j * 0.03597789207803197f);  // ln(10000)/256
    const float ang = (float)t * inv;
    const float pe = (d & 1) ? cosf(ang) : sinf(ang);
    row[d] += pe;
  }
}

// ---------- conv1d k=5 pad=2, C_in=C_out=512 ----------
#define CTT 8
__global__ __launch_bounds__(256) void conv5_kernel(
    const float* __restrict__ X, const float* __restrict__ Wc,
    const float* __restrict__ bias, float* __restrict__ O, int Tt)
{
  __shared__ float xs[CTT + 4][kD];   // 24 KB
  const int b = blockIdx.y;
  const int t0 = blockIdx.x * CTT;
  const int tid = threadIdx.x;
  for (int v = tid; v < (CTT + 4) * (kD / 4); v += 256) {
    const int rr = v >> 7;
    const int dc = (v & 127) << 2;
    const int t = t0 - 2 + rr;
    float4 val = make_float4(0.f, 0.f, 0.f, 0.f);
    if (t >= 0 && t < Tt) val = *(const float4*)&X[((size_t)(b * Tt + t)) * kD + dc];
    xs[rr][dc] = val.x; xs[rr][dc + 1] = val.y; xs[rr][dc + 2] = val.z; xs[rr][dc + 3] = val.w;
  }
  __syncthreads();
#pragma unroll
  for (int pass = 0; pass < 2; ++pass) {
    const int co = tid + pass * 256;
    const float* wrow = Wc + (size_t)co * kD * 5;
    float acc[CTT];
#pragma unroll
    for (int t = 0; t < CTT; ++t) acc[t] = 0.f;
    for (int ci = 0; ci < kD; ++ci) {
      const float w0 = wrow[ci * 5 + 0];
      const float w1 = wrow[ci * 5 + 1];
      const float w2 = wrow[ci * 5 + 2];
      const float w3 = wrow[ci * 5 + 3];
      const float w4 = wrow[ci * 5 + 4];
#pragma unroll
      for (int t = 0; t < CTT; ++t) {
        acc[t] = fmaf(w0, xs[t][ci], acc[t]);
        acc[t] = fmaf(w1, xs[t + 1][ci], acc[t]);
        acc[t] = fmaf(w2, xs[t + 2][ci], acc[t]);
        acc[t] = fmaf(w3, xs[t + 3][ci], acc[t]);
        acc[t] = fmaf(w4, xs[t + 4][ci], acc[t]);
      }
    }
    const float bb = bias[co];
#pragma unroll
    for (int t = 0; t < CTT; ++t)
      O[((size_t)(b * Tt + t0 + t)) * kD + co] = acc[t] + bb;
  }
}

// ---------- small elementwise kernels ----------
__global__ void copy_kernel(const float* __restrict__ X, float* __restrict__ Y2, int n)
{
  const int i = blockIdx.x * 256 + threadIdx.x;
  if (i < n) Y2[i] = X[i];
}
__global__ void add_kernel(float* __restrict__ Y2, const float* __restrict__ X, int n)
{
  const int i = blockIdx.x * 256 + threadIdx.x;
  if (i < n) Y2[i] += X[i];
}
__global__ void avgpool_kernel(const float* __restrict__ X, float* __restrict__ Y2, int Tout, int n)
{
  const int i = blockIdx.x * 256 + threadIdx.x;
  if (i >= n) return;
  const int c = i & (kD - 1);
  const int t = (i >> 9) % Tout;
  const int b = i / (kD * Tout);
  const float* src = X + ((size_t)(b * (2 * Tout) + 2 * t)) * kD + c;
  Y2[i] = 0.5f * (src[0] + src[kD]);
}

extern "C" void kernel_launch(void* const* d_in, const int* in_sizes, int n_in,
                              void* d_out, int out_size, void* d_ws, size_t ws_size,
                              hipStream_t stream)
{
  (void)in_sizes; (void)n_in; (void)out_size; (void)ws_size;
  const float* poses  = (const float*)d_in[0];
  const float* pose_w = (const float*)d_in[1];
  const float* pose_b = (const float*)d_in[2];
  const float* in_w   = (const float*)d_in[3];
  const float* in_b   = (const float*)d_in[4];
  const float* out_w  = (const float*)d_in[5];
  const float* out_b  = (const float*)d_in[6];
  const float* ln1_g  = (const float*)d_in[7];
  const float* ln1_b  = (const float*)d_in[8];
  const float* ffn_w1 = (const float*)d_in[9];
  const float* ffn_b1 = (const float*)d_in[10];
  const float* ffn_w2 = (const float*)d_in[11];
  const float* ffn_b2 = (const float*)d_in[12];
  const float* ln2_g  = (const float*)d_in[13];
  const float* ln2_b  = (const float*)d_in[14];
  const float* tcn1_w = (const float*)d_in[15];
  const float* tcn1_b = (const float*)d_in[16];
  const float* tcn2_w = (const float*)d_in[17];
  const float* tcn2_b = (const float*)d_in[18];
  const float* fc1_w  = (const float*)d_in[19];
  const float* fc1_b  = (const float*)d_in[20];
  const float* fc2_w  = (const float*)d_in[21];
  const float* fc2_b  = (const float*)d_in[22];

  // workspace layout (f32): A | Y | ATT | P | BIG   = 8+8+8+8+32 MB = 64 MB
  float* ws = (float*)d_ws;
  const size_t SZ = (size_t)kB * kT * kD;  // 2,097,152
  float* A   = ws;
  float* Y   = A + SZ;
  float* ATT = Y + SZ;
  float* P   = ATT + SZ;
  float* BIG = P + SZ;                     // 8,388,608 floats (qkv 24MB / ffn-mid 32MB)

  const int M = kB * kT;  // 4096
  dim3 blk(256);

  // embed: A = poses @ pose_w.T + pose_b ; += posenc
  gemm_kernel<<<dim3(kD / GBN, M / GBM), blk, 0, stream>>>(poses, pose_w, pose_b, nullptr, A, M, kD, kIn, 0);
  posenc_kernel<<<M, blk, 0, stream>>>(A);

  for (int l = 0; l < 8; ++l) {
    if (l == 2 || l == 4 || l == 6)
      copy_kernel<<<(int)(SZ / 256), blk, 0, stream>>>(A, P, (int)SZ);

    // qkv = A @ in_w[l].T + in_b[l]
    gemm_kernel<<<dim3(3 * kD / GBN, M / GBM), blk, 0, stream>>>(
        A, in_w + (size_t)l * 3 * kD * kD, in_b + (size_t)l * 3 * kD, nullptr, BIG, M, 3 * kD, kD, 0);
    // ATT = attention(qkv)
    attn_kernel<<<dim3(kT / 16, kH, kB), blk, 0, stream>>>(BIG, ATT);
    // Y = ATT @ out_w[l].T + out_b[l] + A ; LN1 in place
    gemm_kernel<<<dim3(kD / GBN, M / GBM), blk, 0, stream>>>(
        ATT, out_w + (size_t)l * kD * kD, out_b + (size_t)l * kD, A, Y, M, kD, kD, 0);
    ln_kernel<<<M, blk, 0, stream>>>(Y, ln1_g + (size_t)l * kD, ln1_b + (size_t)l * kD);
    // BIG = relu(Y @ ffn_w1[l].T + ffn_b1[l])
    gemm_kernel<<<dim3(kFF / GBN, M / GBM), blk, 0, stream>>>(
        Y, ffn_w1 + (size_t)l * kFF * kD, ffn_b1 + (size_t)l * kFF, nullptr, BIG, M, kFF, kD, 1);
    // A = BIG @ ffn_w2[l].T + ffn_b2[l] + Y ; LN2 in place
    gemm_kernel<<<dim3(kD / GBN, M / GBM), blk, 0, stream>>>(
        BIG, ffn_w2 + (size_t)l * kD * kFF, ffn_b2 + (size_t)l * kD, Y, A, M, kD, kFF, 0);
    ln_kernel<<<M, blk, 0, stream>>>(A, ln2_g + (size_t)l * kD, ln2_b + (size_t)l * kD);

    if (l == 3 || l == 5 || l == 7)
      add_kernel<<<(int)(SZ / 256), blk, 0, stream>>>(A, P, (int)SZ);
  }

  // head
  {
    const int T1 = kT / 2;   // 512
    const int n1 = kB * T1 * kD;
    avgpool_kernel<<<(n1 + 255) / 256, blk, 0, stream>>>(A, Y, T1, n1);
    conv5_kernel<<<dim3(T1 / CTT, kB), blk, 0, stream>>>(Y, tcn1_w, tcn1_b, ATT, T1);
    const int T2 = kT / 4;   // 256
    const int n2 = kB * T2 * kD;
    avgpool_kernel<<<(n2 + 255) / 256, blk, 0, stream>>>(ATT, Y, T2, n2);
    conv5_kernel<<<dim3(T2 / CTT, kB), blk, 0, stream>>>(Y, tcn2_w, tcn2_b, ATT, T2);
    const int Mh = kB * T2;  // 1024
    gemm_kernel<<<dim3(128 / GBN, Mh / GBM), blk, 0, stream>>>(ATT, fc1_w, fc1_b, nullptr, Y, Mh, 128, kD, 0);
    // fc2 writes f32 DIRECTLY to d_out (output dtype is float32 — npz size proves it)
    gemm_kernel<<<dim3((kNCLS + GBN - 1) / GBN, Mh / GBM), blk, 0, stream>>>(
        Y, fc2_w, fc2_b, nullptr, (float*)d_out, Mh, kNCLS, 128, 0);
  }
}

// Round 3
// 4557.789 us; speedup vs baseline: 1.8868x; 1.8868x over previous
//
#include <hip/hip_runtime.h>
#include <hip/hip_bf16.h>

static constexpr int kB = 4;
static constexpr int kT = 1024;
static constexpr int kIn = 172;
static constexpr int kD = 512;
static constexpr int kH = 8;
static constexpr int kHD = 64;
static constexpr int kFF = 2048;
static constexpr int kNCLS = 1296;
static constexpr float kEps = 1e-5f;

typedef __attribute__((ext_vector_type(8))) short bf16x8_t;
typedef __attribute__((ext_vector_type(4))) float f32x4_t;
typedef __attribute__((ext_vector_type(8))) unsigned short u16x8_t;

// round-to-nearest-even f32 -> bf16 bits (finite inputs)
static __device__ __forceinline__ unsigned short f2bf(float f) {
  unsigned int u = __float_as_uint(f);
  unsigned int r = (u + 0x7fffu + ((u >> 16) & 1u)) >> 16;
  return (unsigned short)r;
}

#define GBM 64
#define GBN 64
#define GBK 16
#define LDST 68   // row stride: 68 floats = 272 B = 17*16 B, keeps float4 alignment

// ---------- generic GEMM: C[m,n] = sum_k A[m,k]*W[n,k] + bias[n] (+relu)(+resid) ----------
__global__ __launch_bounds__(256) void gemm_kernel(
    const float* __restrict__ A, const float* __restrict__ W,
    const float* __restrict__ bias, const float* __restrict__ resid,
    float* __restrict__ C, int M, int N, int K, int doRelu)
{
  __shared__ __align__(16) float As[GBK][LDST];
  __shared__ __align__(16) float Ws[GBK][LDST];
  const int tid = threadIdx.x;
  const int bm = blockIdx.y * GBM;
  const int bn = blockIdx.x * GBN;
  const int tx = tid & 15, ty = tid >> 4;
  const int li = tid >> 2;          // 0..63 : row (A) / col (W) within tile
  const int lk = (tid & 3) << 2;    // 0,4,8,12 : k offset

  float acc[4][4];
#pragma unroll
  for (int i = 0; i < 4; ++i)
#pragma unroll
    for (int j = 0; j < 4; ++j) acc[i][j] = 0.f;

  for (int k0 = 0; k0 < K; k0 += GBK) {
    float4 av = make_float4(0.f, 0.f, 0.f, 0.f);
    float4 wv = make_float4(0.f, 0.f, 0.f, 0.f);
    {
      const int m = bm + li;
      if (m < M) {
        if (k0 + lk + 4 <= K) {
          av = *(const float4*)&A[(size_t)m * K + k0 + lk];
        } else {
          float t4[4] = {0.f, 0.f, 0.f, 0.f};
          for (int c = 0; c < 4; ++c) { int k = k0 + lk + c; if (k < K) t4[c] = A[(size_t)m * K + k]; }
          av = make_float4(t4[0], t4[1], t4[2], t4[3]);
        }
      }
      const int n = bn + li;
      if (n < N) {
        if (k0 + lk + 4 <= K) {
          wv = *(const float4*)&W[(size_t)n * K + k0 + lk];
        } else {
          float t4[4] = {0.f, 0.f, 0.f, 0.f};
          for (int c = 0; c < 4; ++c) { int k = k0 + lk + c; if (k < K) t4[c] = W[(size_t)n * K + k]; }
          wv = make_float4(t4[0], t4[1], t4[2], t4[3]);
        }
      }
    }
    __syncthreads();   // protect LDS from previous iteration's readers
    As[lk + 0][li] = av.x; As[lk + 1][li] = av.y; As[lk + 2][li] = av.z; As[lk + 3][li] = av.w;
    Ws[lk + 0][li] = wv.x; Ws[lk + 1][li] = wv.y; Ws[lk + 2][li] = wv.z; Ws[lk + 3][li] = wv.w;
    __syncthreads();
#pragma unroll
    for (int kk = 0; kk < GBK; ++kk) {
      const float4 a4 = *(const float4*)&As[kk][ty << 2];
      const float4 b4 = *(const float4*)&Ws[kk][tx << 2];
      const float a[4] = {a4.x, a4.y, a4.z, a4.w};
      const float b[4] = {b4.x, b4.y, b4.z, b4.w};
#pragma unroll
      for (int i = 0; i < 4; ++i)
#pragma unroll
        for (int j = 0; j < 4; ++j) acc[i][j] = fmaf(a[i], b[j], acc[i][j]);
    }
  }

#pragma unroll
  for (int i = 0; i < 4; ++i) {
    const int m = bm + (ty << 2) + i;
    if (m >= M) continue;
#pragma unroll
    for (int j = 0; j < 4; ++j) {
      const int n = bn + (tx << 2) + j;
      if (n >= N) continue;
      float v = acc[i][j] + bias[n];
      if (doRelu) v = fmaxf(v, 0.f);
      if (resid) v += resid[(size_t)m * N + n];
      C[(size_t)m * N + n] = v;
    }
  }
}

// ---------- LayerNorm (in-place), one block per row of 512 ----------
__global__ __launch_bounds__(256) void ln_kernel(
    float* __restrict__ X, const float* __restrict__ g, const float* __restrict__ bta)
{
  const int row = blockIdx.x;
  const int tid = threadIdx.x;
  float* xr = X + (size_t)row * kD;
  const float x0 = xr[tid];
  const float x1 = xr[tid + 256];
  float s = x0 + x1;
  float q = x0 * x0 + x1 * x1;
#pragma unroll
  for (int off = 32; off > 0; off >>= 1) {
    s += __shfl_down(s, off);
    q += __shfl_down(q, off);
  }
  __shared__ float ss[4], qq[4];
  const int w = tid >> 6;
  if ((tid & 63) == 0) { ss[w] = s; qq[w] = q; }
  __syncthreads();
  const float S = ss[0] + ss[1] + ss[2] + ss[3];
  const float Q = qq[0] + qq[1] + qq[2] + qq[3];
  const float mean = S * (1.f / kD);
  const float var = Q * (1.f / kD) - mean * mean;
  const float inv = rsqrtf(var + kEps);
  xr[tid]       = (x0 - mean) * inv * g[tid] + bta[tid];
  xr[tid + 256] = (x1 - mean) * inv * g[tid + 256] + bta[tid + 256];
}

// ---------- MFMA flash attention (bf16 inputs, f32 softmax/accum) ----------
// grid: (T/64, H, B), block 256 = 4 waves; wave wv owns q-rows [q0+wv*16, +16).
// Per 64-key tile: stage K row-major + V transposed (bf16, stride 72), 8 MFMA QK^T,
// online softmax (16-lane shfl_xor row reduce), P->LDS bf16, 8 MFMA PV.
#define KSTR 72   // LDS row stride in bf16 units; 144 B = 36 dw -> frag reads 2-way (free)
__global__ __launch_bounds__(256) void attn_mfma_kernel(
    const float* __restrict__ qkv, float* __restrict__ O)
{
  const int b = blockIdx.z, h = blockIdx.y;
  const int q0 = blockIdx.x << 6;
  const int tid = threadIdx.x;
  const int wv = tid >> 6, lane = tid & 63;
  const int lr = lane & 15;   // fragment row (A/B) and D-col
  const int lg = lane >> 4;   // k-group; D-rows are lg*4+r

  __shared__ ushort Ks[64 * KSTR];      // K tile, row-major [key][d]
  __shared__ ushort Vt[64 * KSTR];      // V tile, transposed [d][key]
  __shared__ ushort Pl[4][16 * KSTR];   // per-wave P tile [q][key]

  // Q fragments: lane reads Q[q0+wv*16+lr][32*hh + lg*8 .. +8]
  bf16x8_t qa[2];
  {
    const float* qrow = qkv + ((size_t)(b * kT + q0 + wv * 16 + lr)) * (3 * kD) + h * kHD + lg * 8;
#pragma unroll
    for (int hh = 0; hh < 2; ++hh) {
      const float4 v0 = *(const float4*)(qrow + hh * 32);
      const float4 v1 = *(const float4*)(qrow + hh * 32 + 4);
      bf16x8_t t;
      t[0] = (short)f2bf(v0.x); t[1] = (short)f2bf(v0.y);
      t[2] = (short)f2bf(v0.z); t[3] = (short)f2bf(v0.w);
      t[4] = (short)f2bf(v1.x); t[5] = (short)f2bf(v1.y);
      t[6] = (short)f2bf(v1.z); t[7] = (short)f2bf(v1.w);
      qa[hh] = t;
    }
  }

  float m_[4], l_[4];
  f32x4_t oacc[4];
#pragma unroll
  for (int r = 0; r < 4; ++r) { m_[r] = -1e30f; l_[r] = 0.f; }
#pragma unroll
  for (int nb = 0; nb < 4; ++nb) oacc[nb] = (f32x4_t){0.f, 0.f, 0.f, 0.f};

  const int srow = tid >> 2;          // staging row 0..63
  const int sd   = (tid & 3) << 4;    // staging d offset 0,16,32,48

  for (int kt = 0; kt < kT / 64; ++kt) {
    __syncthreads();   // protect Ks/Vt from previous iteration's readers
    {
      const float* kr = qkv + ((size_t)(b * kT + (kt << 6) + srow)) * (3 * kD) + kD + h * kHD + sd;
      const float4 a0 = *(const float4*)(kr + 0);
      const float4 a1 = *(const float4*)(kr + 4);
      const float4 a2 = *(const float4*)(kr + 8);
      const float4 a3 = *(const float4*)(kr + 12);
      u16x8_t w0, w1;
      w0[0] = f2bf(a0.x); w0[1] = f2bf(a0.y); w0[2] = f2bf(a0.z); w0[3] = f2bf(a0.w);
      w0[4] = f2bf(a1.x); w0[5] = f2bf(a1.y); w0[6] = f2bf(a1.z); w0[7] = f2bf(a1.w);
      w1[0] = f2bf(a2.x); w1[1] = f2bf(a2.y); w1[2] = f2bf(a2.z); w1[3] = f2bf(a2.w);
      w1[4] = f2bf(a3.x); w1[5] = f2bf(a3.y); w1[6] = f2bf(a3.z); w1[7] = f2bf(a3.w);
      *(u16x8_t*)&Ks[srow * KSTR + sd]     = w0;
      *(u16x8_t*)&Ks[srow * KSTR + sd + 8] = w1;
      const float* vr = kr + kD;
      const float4 b0 = *(const float4*)(vr + 0);
      const float4 b1 = *(const float4*)(vr + 4);
      const float4 b2 = *(const float4*)(vr + 8);
      const float4 b3 = *(const float4*)(vr + 12);
      float vv[16] = {b0.x, b0.y, b0.z, b0.w, b1.x, b1.y, b1.z, b1.w,
                      b2.x, b2.y, b2.z, b2.w, b3.x, b3.y, b3.z, b3.w};
#pragma unroll
      for (int e = 0; e < 16; ++e)
        Vt[(sd + e) * KSTR + srow] = f2bf(vv[e]);
    }
    __syncthreads();

    // QK^T: 4 col-blocks x (2 MFMA over d)
    f32x4_t s[4];
#pragma unroll
    for (int cb = 0; cb < 4; ++cb) {
      const ushort* kb = &Ks[(cb * 16 + lr) * KSTR + lg * 8];
      const bf16x8_t k0 = *(const bf16x8_t*)kb;
      const bf16x8_t k1 = *(const bf16x8_t*)(kb + 32);
      f32x4_t acc = (f32x4_t){0.f, 0.f, 0.f, 0.f};
      acc = __builtin_amdgcn_mfma_f32_16x16x32_bf16(qa[0], k0, acc, 0, 0, 0);
      acc = __builtin_amdgcn_mfma_f32_16x16x32_bf16(qa[1], k1, acc, 0, 0, 0);
#pragma unroll
      for (int r = 0; r < 4; ++r) acc[r] *= 0.125f;   // 1/sqrt(64)
      s[cb] = acc;
    }

    // online softmax per row (lane's rows: lg*4+r; cols: cb*16+lr)
#pragma unroll
    for (int r = 0; r < 4; ++r) {
      float mx = fmaxf(fmaxf(s[0][r], s[1][r]), fmaxf(s[2][r], s[3][r]));
      mx = fmaxf(mx, __shfl_xor(mx, 1));
      mx = fmaxf(mx, __shfl_xor(mx, 2));
      mx = fmaxf(mx, __shfl_xor(mx, 4));
      mx = fmaxf(mx, __shfl_xor(mx, 8));
      const float mnew = fmaxf(m_[r], mx);
      const float alpha = __expf(m_[r] - mnew);   // 0 on first tile
      float sum = 0.f;
#pragma unroll
      for (int cb = 0; cb < 4; ++cb) {
        const float p = __expf(s[cb][r] - mnew);
        s[cb][r] = p;
        sum += p;
      }
      sum += __shfl_xor(sum, 1);
      sum += __shfl_xor(sum, 2);
      sum += __shfl_xor(sum, 4);
      sum += __shfl_xor(sum, 8);
      l_[r] = l_[r] * alpha + sum;
      m_[r] = mnew;
#pragma unroll
      for (int nb = 0; nb < 4; ++nb) oacc[nb][r] *= alpha;
#pragma unroll
      for (int cb = 0; cb < 4; ++cb)
        Pl[wv][(lg * 4 + r) * KSTR + cb * 16 + lr] = f2bf(s[cb][r]);
    }

    // PV: O[16q][64d] += P[16q][64j] * V[64j][64d]
    const bf16x8_t pa0 = *(const bf16x8_t*)&Pl[wv][lr * KSTR + lg * 8];
    const bf16x8_t pa1 = *(const bf16x8_t*)&Pl[wv][lr * KSTR + 32 + lg * 8];
#pragma unroll
    for (int nb = 0; nb < 4; ++nb) {
      const ushort* vb = &Vt[(nb * 16 + lr) * KSTR + lg * 8];
      const bf16x8_t v0 = *(const bf16x8_t*)vb;
      const bf16x8_t v1 = *(const bf16x8_t*)(vb + 32);
      oacc[nb] = __builtin_amdgcn_mfma_f32_16x16x32_bf16(pa0, v0, oacc[nb], 0, 0, 0);
      oacc[nb] = __builtin_amdgcn_mfma_f32_16x16x32_bf16(pa1, v1, oacc[nb], 0, 0, 0);
    }
  }

  // epilogue: normalize and store (D layout: row=lg*4+r, col=nb*16+lr)
#pragma unroll
  for (int nb = 0; nb < 4; ++nb) {
#pragma unroll
    for (int r = 0; r < 4; ++r) {
      const int row = lg * 4 + r;
      const int col = nb * 16 + lr;
      O[((size_t)(b * kT + q0 + wv * 16 + row)) * kD + h * kHD + col] = oacc[nb][r] / l_[r];
    }
  }
}

// ---------- positional encoding add ----------
__global__ __launch_bounds__(256) void posenc_kernel(float* __restrict__ X)
{
  const int bt = blockIdx.x;
  const int t = bt & (kT - 1);
  float* row = X + (size_t)bt * kD;
#pragma unroll
  for (int p = 0; p < 2; ++p) {
    const int d = threadIdx.x + p * 256;
    const int j = d >> 1;
    const float inv = expf(-(float)j * 0.03597789207803197f);  // ln(10000)/256
    const float ang = (float)t * inv;
    const float pe = (d & 1) ? cosf(ang) : sinf(ang);
    row[d] += pe;
  }
}

// ---------- conv1d k=5 pad=2, C_in=C_out=512 ----------
#define CTT 8
__global__ __launch_bounds__(256) void conv5_kernel(
    const float* __restrict__ X, const float* __restrict__ Wc,
    const float* __restrict__ bias, float* __restrict__ O, int Tt)
{
  __shared__ float xs[CTT + 4][kD];   // 24 KB
  const int b = blockIdx.y;
  const int t0 = blockIdx.x * CTT;
  const int tid = threadIdx.x;
  for (int v = tid; v < (CTT + 4) * (kD / 4); v += 256) {
    const int rr = v >> 7;
    const int dc = (v & 127) << 2;
    const int t = t0 - 2 + rr;
    float4 val = make_float4(0.f, 0.f, 0.f, 0.f);
    if (t >= 0 && t < Tt) val = *(const float4*)&X[((size_t)(b * Tt + t)) * kD + dc];
    xs[rr][dc] = val.x; xs[rr][dc + 1] = val.y; xs[rr][dc + 2] = val.z; xs[rr][dc + 3] = val.w;
  }
  __syncthreads();
#pragma unroll
  for (int pass = 0; pass < 2; ++pass) {
    const int co = tid + pass * 256;
    const float* wrow = Wc + (size_t)co * kD * 5;
    float acc[CTT];
#pragma unroll
    for (int t = 0; t < CTT; ++t) acc[t] = 0.f;
    for (int ci = 0; ci < kD; ++ci) {
      const float w0 = wrow[ci * 5 + 0];
      const float w1 = wrow[ci * 5 + 1];
      const float w2 = wrow[ci * 5 + 2];
      const float w3 = wrow[ci * 5 + 3];
      const float w4 = wrow[ci * 5 + 4];
#pragma unroll
      for (int t = 0; t < CTT; ++t) {
        acc[t] = fmaf(w0, xs[t][ci], acc[t]);
        acc[t] = fmaf(w1, xs[t + 1][ci], acc[t]);
        acc[t] = fmaf(w2, xs[t + 2][ci], acc[t]);
        acc[t] = fmaf(w3, xs[t + 3][ci], acc[t]);
        acc[t] = fmaf(w4, xs[t + 4][ci], acc[t]);
      }
    }
    const float bb = bias[co];
#pragma unroll
    for (int t = 0; t < CTT; ++t)
      O[((size_t)(b * Tt + t0 + t)) * kD + co] = acc[t] + bb;
  }
}

// ---------- small elementwise kernels ----------
__global__ void copy_kernel(const float* __restrict__ X, float* __restrict__ Y2, int n)
{
  const int i = blockIdx.x * 256 + threadIdx.x;
  if (i < n) Y2[i] = X[i];
}
__global__ void add_kernel(float* __restrict__ Y2, const float* __restrict__ X, int n)
{
  const int i = blockIdx.x * 256 + threadIdx.x;
  if (i < n) Y2[i] += X[i];
}
__global__ void avgpool_kernel(const float* __restrict__ X, float* __restrict__ Y2, int Tout, int n)
{
  const int i = blockIdx.x * 256 + threadIdx.x;
  if (i >= n) return;
  const int c = i & (kD - 1);
  const int t = (i >> 9) % Tout;
  const int b = i / (kD * Tout);
  const float* src = X + ((size_t)(b * (2 * Tout) + 2 * t)) * kD + c;
  Y2[i] = 0.5f * (src[0] + src[kD]);
}

extern "C" void kernel_launch(void* const* d_in, const int* in_sizes, int n_in,
                              void* d_out, int out_size, void* d_ws, size_t ws_size,
                              hipStream_t stream)
{
  (void)in_sizes; (void)n_in; (void)out_size; (void)ws_size;
  const float* poses  = (const float*)d_in[0];
  const float* pose_w = (const float*)d_in[1];
  const float* pose_b = (const float*)d_in[2];
  const float* in_w   = (const float*)d_in[3];
  const float* in_b   = (const float*)d_in[4];
  const float* out_w  = (const float*)d_in[5];
  const float* out_b  = (const float*)d_in[6];
  const float* ln1_g  = (const float*)d_in[7];
  const float* ln1_b  = (const float*)d_in[8];
  const float* ffn_w1 = (const float*)d_in[9];
  const float* ffn_b1 = (const float*)d_in[10];
  const float* ffn_w2 = (const float*)d_in[11];
  const float* ffn_b2 = (const float*)d_in[12];
  const float* ln2_g  = (const float*)d_in[13];
  const float* ln2_b  = (const float*)d_in[14];
  const float* tcn1_w = (const float*)d_in[15];
  const float* tcn1_b = (const float*)d_in[16];
  const float* tcn2_w = (const float*)d_in[17];
  const float* tcn2_b = (const float*)d_in[18];
  const float* fc1_w  = (const float*)d_in[19];
  const float* fc1_b  = (const float*)d_in[20];
  const float* fc2_w  = (const float*)d_in[21];
  const float* fc2_b  = (const float*)d_in[22];

  // workspace layout (f32): A | Y | ATT | P | BIG   = 8+8+8+8+32 MB = 64 MB
  float* ws = (float*)d_ws;
  const size_t SZ = (size_t)kB * kT * kD;  // 2,097,152
  float* A   = ws;
  float* Y   = A + SZ;
  float* ATT = Y + SZ;
  float* P   = ATT + SZ;
  float* BIG = P + SZ;                     // 8,388,608 floats (qkv 24MB / ffn-mid 32MB)

  const int M = kB * kT;  // 4096
  dim3 blk(256);

  // embed: A = poses @ pose_w.T + pose_b ; += posenc
  gemm_kernel<<<dim3(kD / GBN, M / GBM), blk, 0, stream>>>(poses, pose_w, pose_b, nullptr, A, M, kD, kIn, 0);
  posenc_kernel<<<M, blk, 0, stream>>>(A);

  for (int l = 0; l < 8; ++l) {
    if (l == 2 || l == 4 || l == 6)
      copy_kernel<<<(int)(SZ / 256), blk, 0, stream>>>(A, P, (int)SZ);

    // qkv = A @ in_w[l].T + in_b[l]
    gemm_kernel<<<dim3(3 * kD / GBN, M / GBM), blk, 0, stream>>>(
        A, in_w + (size_t)l * 3 * kD * kD, in_b + (size_t)l * 3 * kD, nullptr, BIG, M, 3 * kD, kD, 0);
    // ATT = attention(qkv)  — MFMA flash
    attn_mfma_kernel<<<dim3(kT / 64, kH, kB), blk, 0, stream>>>(BIG, ATT);
    // Y = ATT @ out_w[l].T + out_b[l] + A ; LN1 in place
    gemm_kernel<<<dim3(kD / GBN, M / GBM), blk, 0, stream>>>(
        ATT, out_w + (size_t)l * kD * kD, out_b + (size_t)l * kD, A, Y, M, kD, kD, 0);
    ln_kernel<<<M, blk, 0, stream>>>(Y, ln1_g + (size_t)l * kD, ln1_b + (size_t)l * kD);
    // BIG = relu(Y @ ffn_w1[l].T + ffn_b1[l])
    gemm_kernel<<<dim3(kFF / GBN, M / GBM), blk, 0, stream>>>(
        Y, ffn_w1 + (size_t)l * kFF * kD, ffn_b1 + (size_t)l * kFF, nullptr, BIG, M, kFF, kD, 1);
    // A = BIG @ ffn_w2[l].T + ffn_b2[l] + Y ; LN2 in place
    gemm_kernel<<<dim3(kD / GBN, M / GBM), blk, 0, stream>>>(
        BIG, ffn_w2 + (size_t)l * kD * kFF, ffn_b2 + (size_t)l * kD, Y, A, M, kD, kFF, 0);
    ln_kernel<<<M, blk, 0, stream>>>(A, ln2_g + (size_t)l * kD, ln2_b + (size_t)l * kD);

    if (l == 3 || l == 5 || l == 7)
      add_kernel<<<(int)(SZ / 256), blk, 0, stream>>>(A, P, (int)SZ);
  }

  // head
  {
    const int T1 = kT / 2;   // 512
    const int n1 = kB * T1 * kD;
    avgpool_kernel<<<(n1 + 255) / 256, blk, 0, stream>>>(A, Y, T1, n1);
    conv5_kernel<<<dim3(T1 / CTT, kB), blk, 0, stream>>>(Y, tcn1_w, tcn1_b, ATT, T1);
    const int T2 = kT / 4;   // 256
    const int n2 = kB * T2 * kD;
    avgpool_kernel<<<(n2 + 255) / 256, blk, 0, stream>>>(ATT, Y, T2, n2);
    conv5_kernel<<<dim3(T2 / CTT, kB), blk, 0, stream>>>(Y, tcn2_w, tcn2_b, ATT, T2);
    const int Mh = kB * T2;  // 1024
    gemm_kernel<<<dim3(128 / GBN, Mh / GBM), blk, 0, stream>>>(ATT, fc1_w, fc1_b, nullptr, Y, Mh, 128, kD, 0);
    // fc2 writes f32 DIRECTLY to d_out (output dtype is float32)
    gemm_kernel<<<dim3((kNCLS + GBN - 1) / GBN, Mh / GBM), blk, 0, stream>>>(
        Y, fc2_w, fc2_b, nullptr, (float*)d_out, Mh, kNCLS, 128, 0);
  }
}

// Round 4
// 2020.801 us; speedup vs baseline: 4.2556x; 2.2554x over previous
//
#include <hip/hip_runtime.h>
#include <hip/hip_bf16.h>

static constexpr int kB = 4;
static constexpr int kT = 1024;
static constexpr int kIn = 172;
static constexpr int kD = 512;
static constexpr int kH = 8;
static constexpr int kHD = 64;
static constexpr int kFF = 2048;
static constexpr int kNCLS = 1296;
static constexpr float kEps = 1e-5f;

typedef __attribute__((ext_vector_type(8))) short bf16x8_t;
typedef __attribute__((ext_vector_type(4))) float f32x4_t;
typedef __attribute__((ext_vector_type(8))) unsigned short u16x8_t;

// round-to-nearest-even f32 -> bf16 bits (finite inputs)
static __device__ __forceinline__ unsigned short f2bf(float f) {
  unsigned int u = __float_as_uint(f);
  unsigned int r = (u + 0x7fffu + ((u >> 16) & 1u)) >> 16;
  return (unsigned short)r;
}

// ================= MFMA bf16 GEMM =================
// C[m,n] = sum_k A[m,k]*W[n,k] + bias[n] (+relu) (+resid, f32)
// A,W are f32 in global; staged to LDS as bf16 (reg-staged cvt).
// BN=64, BK=32 fixed; BM/MREP templated. 256 threads = 4 waves (2M x 2N),
// wave tile = MREP*16 x 32. Requires M%BM==0, N%64==0, K%32==0.
template<int BM, int MREP>
__global__ __launch_bounds__(256) void mfma_gemm_kernel(
    const float* __restrict__ A, const float* __restrict__ W,
    const float* __restrict__ bias, const float* __restrict__ resid,
    float* __restrict__ C, int M, int N, int K, int doRelu)
{
  constexpr int SRD = 40;              // LDS row stride (ushort): 80 B -> 2-way banks (free)
  constexpr int GA = BM * 4 / 256;     // A 8-elem groups per thread
  __shared__ ushort As[BM * SRD];
  __shared__ ushort Bs[64 * SRD];
  const int tid = threadIdx.x;
  const int bm = blockIdx.y * BM, bn = blockIdx.x * 64;
  const int wv = tid >> 6, lane = tid & 63;
  const int lr = lane & 15, lg = lane >> 4;
  const int wr = wv >> 1, wc = wv & 1;

  f32x4_t acc[MREP][2];
#pragma unroll
  for (int mr = 0; mr < MREP; ++mr)
#pragma unroll
    for (int nr = 0; nr < 2; ++nr) acc[mr][nr] = (f32x4_t){0.f, 0.f, 0.f, 0.f};

  float4 pa[GA][2];
  float4 pb[2];

  auto loadA = [&](int k0) {
#pragma unroll
    for (int i = 0; i < GA; ++i) {
      const int g = tid + i * 256;
      const int row = g >> 2, seg = g & 3;
      const float* p = A + (size_t)(bm + row) * K + k0 + seg * 8;
      pa[i][0] = *(const float4*)p;
      pa[i][1] = *(const float4*)(p + 4);
    }
  };
  auto loadB = [&](int k0) {
    const int row = tid >> 2, seg = tid & 3;
    const float* p = W + (size_t)(bn + row) * K + k0 + seg * 8;
    pb[0] = *(const float4*)p;
    pb[1] = *(const float4*)(p + 4);
  };
  auto storeLDS = [&]() {
#pragma unroll
    for (int i = 0; i < GA; ++i) {
      const int g = tid + i * 256;
      const int row = g >> 2, seg = g & 3;
      u16x8_t t;
      t[0] = f2bf(pa[i][0].x); t[1] = f2bf(pa[i][0].y);
      t[2] = f2bf(pa[i][0].z); t[3] = f2bf(pa[i][0].w);
      t[4] = f2bf(pa[i][1].x); t[5] = f2bf(pa[i][1].y);
      t[6] = f2bf(pa[i][1].z); t[7] = f2bf(pa[i][1].w);
      *(u16x8_t*)&As[row * SRD + seg * 8] = t;
    }
    {
      const int row = tid >> 2, seg = tid & 3;
      u16x8_t t;
      t[0] = f2bf(pb[0].x); t[1] = f2bf(pb[0].y);
      t[2] = f2bf(pb[0].z); t[3] = f2bf(pb[0].w);
      t[4] = f2bf(pb[1].x); t[5] = f2bf(pb[1].y);
      t[6] = f2bf(pb[1].z); t[7] = f2bf(pb[1].w);
      *(u16x8_t*)&Bs[row * SRD + seg * 8] = t;
    }
  };

  loadA(0); loadB(0);
  storeLDS();
  __syncthreads();

  const int nsteps = K >> 5;
  for (int s = 0; s < nsteps; ++s) {
    const int kn = (s + 1) << 5;
    const bool more = kn < K;
    if (more) { loadA(kn); loadB(kn); }   // prefetch overlaps MFMA below

    bf16x8_t af[MREP];
#pragma unroll
    for (int mr = 0; mr < MREP; ++mr)
      af[mr] = *(const bf16x8_t*)&As[(wr * MREP * 16 + mr * 16 + lr) * SRD + lg * 8];
#pragma unroll
    for (int nr = 0; nr < 2; ++nr) {
      const bf16x8_t bf = *(const bf16x8_t*)&Bs[(wc * 32 + nr * 16 + lr) * SRD + lg * 8];
#pragma unroll
      for (int mr = 0; mr < MREP; ++mr)
        acc[mr][nr] = __builtin_amdgcn_mfma_f32_16x16x32_bf16(af[mr], bf, acc[mr][nr], 0, 0, 0);
    }
    __syncthreads();
    if (more) { storeLDS(); __syncthreads(); }
  }

  // epilogue: D layout row = lg*4+v, col = lr (verified mapping)
#pragma unroll
  for (int mr = 0; mr < MREP; ++mr) {
#pragma unroll
    for (int v = 0; v < 4; ++v) {
      const int m = bm + wr * MREP * 16 + mr * 16 + lg * 4 + v;
#pragma unroll
      for (int nr = 0; nr < 2; ++nr) {
        const int n = bn + wc * 32 + nr * 16 + lr;
        float val = acc[mr][nr][v] + bias[n];
        if (doRelu) val = fmaxf(val, 0.f);
        if (resid) val += resid[(size_t)m * N + n];
        C[(size_t)m * N + n] = val;
      }
    }
  }
}

// ================= legacy f32 GEMM (odd shapes: embed K=172, fc1, fc2 N=1296) =================
#define GBM 64
#define GBN 64
#define GBK 16
#define LDST 68

__global__ __launch_bounds__(256) void gemm_kernel(
    const float* __restrict__ A, const float* __restrict__ W,
    const float* __restrict__ bias, const float* __restrict__ resid,
    float* __restrict__ C, int M, int N, int K, int doRelu)
{
  __shared__ __align__(16) float As[GBK][LDST];
  __shared__ __align__(16) float Ws[GBK][LDST];
  const int tid = threadIdx.x;
  const int bm = blockIdx.y * GBM;
  const int bn = blockIdx.x * GBN;
  const int tx = tid & 15, ty = tid >> 4;
  const int li = tid >> 2;
  const int lk = (tid & 3) << 2;

  float acc[4][4];
#pragma unroll
  for (int i = 0; i < 4; ++i)
#pragma unroll
    for (int j = 0; j < 4; ++j) acc[i][j] = 0.f;

  for (int k0 = 0; k0 < K; k0 += GBK) {
    float4 av = make_float4(0.f, 0.f, 0.f, 0.f);
    float4 wv = make_float4(0.f, 0.f, 0.f, 0.f);
    {
      const int m = bm + li;
      if (m < M) {
        if (k0 + lk + 4 <= K) {
          av = *(const float4*)&A[(size_t)m * K + k0 + lk];
        } else {
          float t4[4] = {0.f, 0.f, 0.f, 0.f};
          for (int c = 0; c < 4; ++c) { int k = k0 + lk + c; if (k < K) t4[c] = A[(size_t)m * K + k]; }
          av = make_float4(t4[0], t4[1], t4[2], t4[3]);
        }
      }
      const int n = bn + li;
      if (n < N) {
        if (k0 + lk + 4 <= K) {
          wv = *(const float4*)&W[(size_t)n * K + k0 + lk];
        } else {
          float t4[4] = {0.f, 0.f, 0.f, 0.f};
          for (int c = 0; c < 4; ++c) { int k = k0 + lk + c; if (k < K) t4[c] = W[(size_t)n * K + k]; }
          wv = make_float4(t4[0], t4[1], t4[2], t4[3]);
        }
      }
    }
    __syncthreads();
    As[lk + 0][li] = av.x; As[lk + 1][li] = av.y; As[lk + 2][li] = av.z; As[lk + 3][li] = av.w;
    Ws[lk + 0][li] = wv.x; Ws[lk + 1][li] = wv.y; Ws[lk + 2][li] = wv.z; Ws[lk + 3][li] = wv.w;
    __syncthreads();
#pragma unroll
    for (int kk = 0; kk < GBK; ++kk) {
      const float4 a4 = *(const float4*)&As[kk][ty << 2];
      const float4 b4 = *(const float4*)&Ws[kk][tx << 2];
      const float a[4] = {a4.x, a4.y, a4.z, a4.w};
      const float b[4] = {b4.x, b4.y, b4.z, b4.w};
#pragma unroll
      for (int i = 0; i < 4; ++i)
#pragma unroll
        for (int j = 0; j < 4; ++j) acc[i][j] = fmaf(a[i], b[j], acc[i][j]);
    }
  }

#pragma unroll
  for (int i = 0; i < 4; ++i) {
    const int m = bm + (ty << 2) + i;
    if (m >= M) continue;
#pragma unroll
    for (int j = 0; j < 4; ++j) {
      const int n = bn + (tx << 2) + j;
      if (n >= N) continue;
      float v = acc[i][j] + bias[n];
      if (doRelu) v = fmaxf(v, 0.f);
      if (resid) v += resid[(size_t)m * N + n];
      C[(size_t)m * N + n] = v;
    }
  }
}

// ---------- LayerNorm (in-place), one block per row of 512 ----------
__global__ __launch_bounds__(256) void ln_kernel(
    float* __restrict__ X, const float* __restrict__ g, const float* __restrict__ bta)
{
  const int row = blockIdx.x;
  const int tid = threadIdx.x;
  float* xr = X + (size_t)row * kD;
  const float x0 = xr[tid];
  const float x1 = xr[tid + 256];
  float s = x0 + x1;
  float q = x0 * x0 + x1 * x1;
#pragma unroll
  for (int off = 32; off > 0; off >>= 1) {
    s += __shfl_down(s, off);
    q += __shfl_down(q, off);
  }
  __shared__ float ss[4], qq[4];
  const int w = tid >> 6;
  if ((tid & 63) == 0) { ss[w] = s; qq[w] = q; }
  __syncthreads();
  const float S = ss[0] + ss[1] + ss[2] + ss[3];
  const float Q = qq[0] + qq[1] + qq[2] + qq[3];
  const float mean = S * (1.f / kD);
  const float var = Q * (1.f / kD) - mean * mean;
  const float inv = rsqrtf(var + kEps);
  xr[tid]       = (x0 - mean) * inv * g[tid] + bta[tid];
  xr[tid + 256] = (x1 - mean) * inv * g[tid + 256] + bta[tid + 256];
}

// ---------- MFMA flash attention (bf16 inputs, f32 softmax/accum) ----------
#define KSTR 72
__global__ __launch_bounds__(256) void attn_mfma_kernel(
    const float* __restrict__ qkv, float* __restrict__ O)
{
  const int b = blockIdx.z, h = blockIdx.y;
  const int q0 = blockIdx.x << 6;
  const int tid = threadIdx.x;
  const int wv = tid >> 6, lane = tid & 63;
  const int lr = lane & 15;
  const int lg = lane >> 4;

  __shared__ ushort Ks[64 * KSTR];
  __shared__ ushort Vt[64 * KSTR];
  __shared__ ushort Pl[4][16 * KSTR];

  bf16x8_t qa[2];
  {
    const float* qrow = qkv + ((size_t)(b * kT + q0 + wv * 16 + lr)) * (3 * kD) + h * kHD + lg * 8;
#pragma unroll
    for (int hh = 0; hh < 2; ++hh) {
      const float4 v0 = *(const float4*)(qrow + hh * 32);
      const float4 v1 = *(const float4*)(qrow + hh * 32 + 4);
      bf16x8_t t;
      t[0] = (short)f2bf(v0.x); t[1] = (short)f2bf(v0.y);
      t[2] = (short)f2bf(v0.z); t[3] = (short)f2bf(v0.w);
      t[4] = (short)f2bf(v1.x); t[5] = (short)f2bf(v1.y);
      t[6] = (short)f2bf(v1.z); t[7] = (short)f2bf(v1.w);
      qa[hh] = t;
    }
  }

  float m_[4], l_[4];
  f32x4_t oacc[4];
#pragma unroll
  for (int r = 0; r < 4; ++r) { m_[r] = -1e30f; l_[r] = 0.f; }
#pragma unroll
  for (int nb = 0; nb < 4; ++nb) oacc[nb] = (f32x4_t){0.f, 0.f, 0.f, 0.f};

  const int srow = tid >> 2;
  const int sd   = (tid & 3) << 4;

  for (int kt = 0; kt < kT / 64; ++kt) {
    __syncthreads();
    {
      const float* kr = qkv + ((size_t)(b * kT + (kt << 6) + srow)) * (3 * kD) + kD + h * kHD + sd;
      const float4 a0 = *(const float4*)(kr + 0);
      const float4 a1 = *(const float4*)(kr + 4);
      const float4 a2 = *(const float4*)(kr + 8);
      const float4 a3 = *(const float4*)(kr + 12);
      u16x8_t w0, w1;
      w0[0] = f2bf(a0.x); w0[1] = f2bf(a0.y); w0[2] = f2bf(a0.z); w0[3] = f2bf(a0.w);
      w0[4] = f2bf(a1.x); w0[5] = f2bf(a1.y); w0[6] = f2bf(a1.z); w0[7] = f2bf(a1.w);
      w1[0] = f2bf(a2.x); w1[1] = f2bf(a2.y); w1[2] = f2bf(a2.z); w1[3] = f2bf(a2.w);
      w1[4] = f2bf(a3.x); w1[5] = f2bf(a3.y); w1[6] = f2bf(a3.z); w1[7] = f2bf(a3.w);
      *(u16x8_t*)&Ks[srow * KSTR + sd]     = w0;
      *(u16x8_t*)&Ks[srow * KSTR + sd + 8] = w1;
      const float* vr = kr + kD;
      const float4 b0 = *(const float4*)(vr + 0);
      const float4 b1 = *(const float4*)(vr + 4);
      const float4 b2 = *(const float4*)(vr + 8);
      const float4 b3 = *(const float4*)(vr + 12);
      float vv[16] = {b0.x, b0.y, b0.z, b0.w, b1.x, b1.y, b1.z, b1.w,
                      b2.x, b2.y, b2.z, b2.w, b3.x, b3.y, b3.z, b3.w};
#pragma unroll
      for (int e = 0; e < 16; ++e)
        Vt[(sd + e) * KSTR + srow] = f2bf(vv[e]);
    }
    __syncthreads();

    f32x4_t s[4];
#pragma unroll
    for (int cb = 0; cb < 4; ++cb) {
      const ushort* kb = &Ks[(cb * 16 + lr) * KSTR + lg * 8];
      const bf16x8_t k0 = *(const bf16x8_t*)kb;
      const bf16x8_t k1 = *(const bf16x8_t*)(kb + 32);
      f32x4_t acc = (f32x4_t){0.f, 0.f, 0.f, 0.f};
      acc = __builtin_amdgcn_mfma_f32_16x16x32_bf16(qa[0], k0, acc, 0, 0, 0);
      acc = __builtin_amdgcn_mfma_f32_16x16x32_bf16(qa[1], k1, acc, 0, 0, 0);
#pragma unroll
      for (int r = 0; r < 4; ++r) acc[r] *= 0.125f;
      s[cb] = acc;
    }

#pragma unroll
    for (int r = 0; r < 4; ++r) {
      float mx = fmaxf(fmaxf(s[0][r], s[1][r]), fmaxf(s[2][r], s[3][r]));
      mx = fmaxf(mx, __shfl_xor(mx, 1));
      mx = fmaxf(mx, __shfl_xor(mx, 2));
      mx = fmaxf(mx, __shfl_xor(mx, 4));
      mx = fmaxf(mx, __shfl_xor(mx, 8));
      const float mnew = fmaxf(m_[r], mx);
      const float alpha = __expf(m_[r] - mnew);
      float sum = 0.f;
#pragma unroll
      for (int cb = 0; cb < 4; ++cb) {
        const float p = __expf(s[cb][r] - mnew);
        s[cb][r] = p;
        sum += p;
      }
      sum += __shfl_xor(sum, 1);
      sum += __shfl_xor(sum, 2);
      sum += __shfl_xor(sum, 4);
      sum += __shfl_xor(sum, 8);
      l_[r] = l_[r] * alpha + sum;
      m_[r] = mnew;
#pragma unroll
      for (int nb = 0; nb < 4; ++nb) oacc[nb][r] *= alpha;
#pragma unroll
      for (int cb = 0; cb < 4; ++cb)
        Pl[wv][(lg * 4 + r) * KSTR + cb * 16 + lr] = f2bf(s[cb][r]);
    }

    const bf16x8_t pa0 = *(const bf16x8_t*)&Pl[wv][lr * KSTR + lg * 8];
    const bf16x8_t pa1 = *(const bf16x8_t*)&Pl[wv][lr * KSTR + 32 + lg * 8];
#pragma unroll
    for (int nb = 0; nb < 4; ++nb) {
      const ushort* vb = &Vt[(nb * 16 + lr) * KSTR + lg * 8];
      const bf16x8_t v0 = *(const bf16x8_t*)vb;
      const bf16x8_t v1 = *(const bf16x8_t*)(vb + 32);
      oacc[nb] = __builtin_amdgcn_mfma_f32_16x16x32_bf16(pa0, v0, oacc[nb], 0, 0, 0);
      oacc[nb] = __builtin_amdgcn_mfma_f32_16x16x32_bf16(pa1, v1, oacc[nb], 0, 0, 0);
    }
  }

#pragma unroll
  for (int nb = 0; nb < 4; ++nb) {
#pragma unroll
    for (int r = 0; r < 4; ++r) {
      const int row = lg * 4 + r;
      const int col = nb * 16 + lr;
      O[((size_t)(b * kT + q0 + wv * 16 + row)) * kD + h * kHD + col] = oacc[nb][r] / l_[r];
    }
  }
}

// ---------- positional encoding add ----------
__global__ __launch_bounds__(256) void posenc_kernel(float* __restrict__ X)
{
  const int bt = blockIdx.x;
  const int t = bt & (kT - 1);
  float* row = X + (size_t)bt * kD;
#pragma unroll
  for (int p = 0; p < 2; ++p) {
    const int d = threadIdx.x + p * 256;
    const int j = d >> 1;
    const float inv = expf(-(float)j * 0.03597789207803197f);  // ln(10000)/256
    const float ang = (float)t * inv;
    const float pe = (d & 1) ? cosf(ang) : sinf(ang);
    row[d] += pe;
  }
}

// ---------- conv as GEMM: fused avgpool + im2col (f32 out) ----------
// X: [B][2*Tt][512] f32 -> X5: [B*Tt][5*512] f32, X5[b*Tt+t][tap*512+ci] =
//   0.5*(X[b][2(t+tap-2)][ci] + X[b][2(t+tap-2)+1][ci]) or 0 if OOB.
__global__ void im2col_pool_kernel(const float* __restrict__ X, float* __restrict__ X5,
                                   int Tt, int n4)
{
  const int idx = blockIdx.x * 256 + threadIdx.x;
  if (idx >= n4) return;
  const int ci4 = idx & 127;
  int r = idx >> 7;
  const int tap = r % 5; r /= 5;
  const int t = r % Tt;
  const int b = r / Tt;
  const int ts = t + tap - 2;
  float4 v = make_float4(0.f, 0.f, 0.f, 0.f);
  if (ts >= 0 && ts < Tt) {
    const float* p = X + ((size_t)(b * 2 * Tt + 2 * ts)) * kD + ci4 * 4;
    const float4 x0 = *(const float4*)p;
    const float4 x1 = *(const float4*)(p + kD);
    v.x = 0.5f * (x0.x + x1.x); v.y = 0.5f * (x0.y + x1.y);
    v.z = 0.5f * (x0.z + x1.z); v.w = 0.5f * (x0.w + x1.w);
  }
  *(float4*)&X5[((size_t)(b * Tt + t)) * 2560 + tap * kD + ci4 * 4] = v;
}

// conv weight transpose: Wt[co][tap*512+ci] = w[co][ci][tap]   (512*512*5 elems)
__global__ void convw_t_kernel(const float* __restrict__ w, float* __restrict__ Wt)
{
  const int idx = blockIdx.x * 256 + threadIdx.x;
  if (idx >= 512 * 512 * 5) return;
  const int ci = idx & 511;
  int r = idx >> 9;
  const int tap = r % 5;
  const int co = r / 5;
  Wt[(size_t)co * 2560 + tap * 512 + ci] = w[(size_t)co * 2560 + ci * 5 + tap];
}

// ---------- small elementwise kernels ----------
__global__ void copy_kernel(const float* __restrict__ X, float* __restrict__ Y2, int n)
{
  const int i = blockIdx.x * 256 + threadIdx.x;
  if (i < n) Y2[i] = X[i];
}
__global__ void add_kernel(float* __restrict__ Y2, const float* __restrict__ X, int n)
{
  const int i = blockIdx.x * 256 + threadIdx.x;
  if (i < n) Y2[i] += X[i];
}

extern "C" void kernel_launch(void* const* d_in, const int* in_sizes, int n_in,
                              void* d_out, int out_size, void* d_ws, size_t ws_size,
                              hipStream_t stream)
{
  (void)in_sizes; (void)n_in; (void)out_size; (void)ws_size;
  const float* poses  = (const float*)d_in[0];
  const float* pose_w = (const float*)d_in[1];
  const float* pose_b = (const float*)d_in[2];
  const float* in_w   = (const float*)d_in[3];
  const float* in_b   = (const float*)d_in[4];
  const float* out_w  = (const float*)d_in[5];
  const float* out_b  = (const float*)d_in[6];
  const float* ln1_g  = (const float*)d_in[7];
  const float* ln1_b  = (const float*)d_in[8];
  const float* ffn_w1 = (const float*)d_in[9];
  const float* ffn_b1 = (const float*)d_in[10];
  const float* ffn_w2 = (const float*)d_in[11];
  const float* ffn_b2 = (const float*)d_in[12];
  const float* ln2_g  = (const float*)d_in[13];
  const float* ln2_b  = (const float*)d_in[14];
  const float* tcn1_w = (const float*)d_in[15];
  const float* tcn1_b = (const float*)d_in[16];
  const float* tcn2_w = (const float*)d_in[17];
  const float* tcn2_b = (const float*)d_in[18];
  const float* fc1_w  = (const float*)d_in[19];
  const float* fc1_b  = (const float*)d_in[20];
  const float* fc2_w  = (const float*)d_in[21];
  const float* fc2_b  = (const float*)d_in[22];

  // workspace layout (f32): A | Y | ATT | P | BIG  = 8+8+8+8+33.5 MB
  float* ws = (float*)d_ws;
  const size_t SZ = (size_t)kB * kT * kD;  // 2,097,152
  float* A   = ws;
  float* Y   = A + SZ;
  float* ATT = Y + SZ;
  float* P   = ATT + SZ;                   // layer skips; conv Wt in head phase
  float* BIG = P + SZ;                     // qkv (24MB) / ffn-mid (32MB) / im2col (21MB)

  const int M = kB * kT;  // 4096
  dim3 blk(256);

  // embed: A = poses @ pose_w.T + pose_b ; += posenc   (K=172 -> legacy f32 gemm)
  gemm_kernel<<<dim3(kD / GBN, M / GBM), blk, 0, stream>>>(poses, pose_w, pose_b, nullptr, A, M, kD, kIn, 0);
  posenc_kernel<<<M, blk, 0, stream>>>(A);

  for (int l = 0; l < 8; ++l) {
    if (l == 2 || l == 4 || l == 6)
      copy_kernel<<<(int)(SZ / 256), blk, 0, stream>>>(A, P, (int)SZ);

    // qkv = A @ in_w[l].T + in_b[l]
    mfma_gemm_kernel<128, 4><<<dim3(3 * kD / 64, M / 128), blk, 0, stream>>>(
        A, in_w + (size_t)l * 3 * kD * kD, in_b + (size_t)l * 3 * kD, nullptr, BIG, M, 3 * kD, kD, 0);
    // ATT = attention(qkv)
    attn_mfma_kernel<<<dim3(kT / 64, kH, kB), blk, 0, stream>>>(BIG, ATT);
    // Y = ATT @ out_w[l].T + out_b[l] + A ; LN1 in place
    mfma_gemm_kernel<128, 4><<<dim3(kD / 64, M / 128), blk, 0, stream>>>(
        ATT, out_w + (size_t)l * kD * kD, out_b + (size_t)l * kD, A, Y, M, kD, kD, 0);
    ln_kernel<<<M, blk, 0, stream>>>(Y, ln1_g + (size_t)l * kD, ln1_b + (size_t)l * kD);
    // BIG = relu(Y @ ffn_w1[l].T + ffn_b1[l])
    mfma_gemm_kernel<128, 4><<<dim3(kFF / 64, M / 128), blk, 0, stream>>>(
        Y, ffn_w1 + (size_t)l * kFF * kD, ffn_b1 + (size_t)l * kFF, nullptr, BIG, M, kFF, kD, 1);
    // A = BIG @ ffn_w2[l].T + ffn_b2[l] + Y ; LN2 in place
    mfma_gemm_kernel<128, 4><<<dim3(kD / 64, M / 128), blk, 0, stream>>>(
        BIG, ffn_w2 + (size_t)l * kD * kFF, ffn_b2 + (size_t)l * kD, Y, A, M, kD, kFF, 0);
    ln_kernel<<<M, blk, 0, stream>>>(A, ln2_g + (size_t)l * kD, ln2_b + (size_t)l * kD);

    if (l == 3 || l == 5 || l == 7)
      add_kernel<<<(int)(SZ / 256), blk, 0, stream>>>(A, P, (int)SZ);
  }

  // head: pool+conv1 -> pool+conv2 -> fc1 -> fc2 (convs as MFMA GEMMs, K=2560)
  {
    const int T1 = kT / 2;   // 512
    const int T2 = kT / 4;   // 256
    // conv1: im2col(pool(A)) @ Wt1
    convw_t_kernel<<<(512 * 512 * 5 + 255) / 256, blk, 0, stream>>>(tcn1_w, P);
    const int n4a = kB * T1 * 5 * (kD / 4);
    im2col_pool_kernel<<<(n4a + 255) / 256, blk, 0, stream>>>(A, BIG, T1, n4a);
    mfma_gemm_kernel<64, 2><<<dim3(kD / 64, kB * T1 / 64), blk, 0, stream>>>(
        BIG, P, tcn1_b, nullptr, Y, kB * T1, kD, 2560, 0);
    // conv2: im2col(pool(Y)) @ Wt2
    convw_t_kernel<<<(512 * 512 * 5 + 255) / 256, blk, 0, stream>>>(tcn2_w, P);
    const int n4b = kB * T2 * 5 * (kD / 4);
    im2col_pool_kernel<<<(n4b + 255) / 256, blk, 0, stream>>>(Y, BIG, T2, n4b);
    mfma_gemm_kernel<64, 2><<<dim3(kD / 64, kB * T2 / 64), blk, 0, stream>>>(
        BIG, P, tcn2_b, nullptr, ATT, kB * T2, kD, 2560, 0);
    // fc1, fc2 (legacy f32 gemm: small / odd N)
    const int Mh = kB * T2;  // 1024
    gemm_kernel<<<dim3(128 / GBN, Mh / GBM), blk, 0, stream>>>(ATT, fc1_w, fc1_b, nullptr, A, Mh, 128, kD, 0);
    gemm_kernel<<<dim3((kNCLS + GBN - 1) / GBN, Mh / GBM), blk, 0, stream>>>(
        A, fc2_w, fc2_b, nullptr, (float*)d_out, Mh, kNCLS, 128, 0);
  }
}

// Round 6
// 1499.571 us; speedup vs baseline: 5.7349x; 1.3476x over previous
//
#include <hip/hip_runtime.h>
#include <hip/hip_bf16.h>

static constexpr int kB = 4;
static constexpr int kT = 1024;
static constexpr int kIn = 172;
static constexpr int kD = 512;
static constexpr int kH = 8;
static constexpr int kHD = 64;
static constexpr int kFF = 2048;
static constexpr int kNCLS = 1296;
static constexpr float kEps = 1e-5f;

typedef __attribute__((ext_vector_type(8))) short bf16x8_t;
typedef __attribute__((ext_vector_type(4))) float f32x4_t;
typedef __attribute__((ext_vector_type(8))) unsigned short u16x8_t;
typedef __attribute__((ext_vector_type(4))) unsigned short u16x4_t;

// round-to-nearest-even f32 -> bf16 bits (finite inputs)
static __device__ __forceinline__ unsigned short f2bf(float f) {
  unsigned int u = __float_as_uint(f);
  unsigned int r = (u + 0x7fffu + ((u >> 16) & 1u)) >> 16;
  return (unsigned short)r;
}

// ---------- f32 -> bf16 bulk convert (n % 8 == 0) ----------
__global__ void cvt_kernel(const float* __restrict__ src, ushort* __restrict__ dst, int n8)
{
  const int i = blockIdx.x * 256 + threadIdx.x;
  if (i >= n8) return;
  const float4 a = *(const float4*)&src[i * 8];
  const float4 b = *(const float4*)&src[i * 8 + 4];
  u16x8_t t;
  t[0] = f2bf(a.x); t[1] = f2bf(a.y); t[2] = f2bf(a.z); t[3] = f2bf(a.w);
  t[4] = f2bf(b.x); t[5] = f2bf(b.y); t[6] = f2bf(b.z); t[7] = f2bf(b.w);
  *(u16x8_t*)&dst[i * 8] = t;
}

// ================= bf16 MFMA GEMM =================
// C[m,n] = sum_k A[m,k]*W[n,k] + bias[n] (+relu) (+resid f32); C f32 and/or Cb bf16.
// BM=MREP*32, BN=NREP*32, BK=64. 256 threads = 4 waves (2Mx2N).
// Requires M%BM==0, N%BN==0, K%64==0.
template<int MREP, int NREP>
__global__ __launch_bounds__(256) void bgemm_kernel(
    const ushort* __restrict__ A, const ushort* __restrict__ W,
    const float* __restrict__ bias, const float* __restrict__ resid,
    float* __restrict__ C, ushort* __restrict__ Cb, int M, int N, int K, int doRelu)
{
  constexpr int BM = MREP * 32, BN = NREP * 32;
  constexpr int SRD = 72;              // ushort row stride (144 B) -> 2-way banks (free)
  constexpr int TPRA = 256 / BM, CSA = 64 / TPRA, NLA = CSA / 8;
  constexpr int TPRB = 256 / BN, CSB = 64 / TPRB, NLB = CSB / 8;
  __shared__ ushort As[BM * SRD];
  __shared__ ushort Bs[BN * SRD];

  const int tid = threadIdx.x;
  // XCD-aware swizzle (grids here are all %8==0, guarded anyway)
  int bid = blockIdx.y * gridDim.x + blockIdx.x;
  const int nwg = gridDim.x * gridDim.y;
  if ((nwg & 7) == 0) bid = (bid & 7) * (nwg >> 3) + (bid >> 3);
  const int bm = (bid / gridDim.x) * BM, bn = (bid % gridDim.x) * BN;

  const int wv = tid >> 6, lane = tid & 63;
  const int lr = lane & 15, lg = lane >> 4;
  const int wr = wv >> 1, wc = wv & 1;

  const int ra = tid / TPRA, ca = (tid % TPRA) * CSA;
  const int rb = tid / TPRB, cb = (tid % TPRB) * CSB;

  f32x4_t acc[MREP][NREP];
#pragma unroll
  for (int mr = 0; mr < MREP; ++mr)
#pragma unroll
    for (int nr = 0; nr < NREP; ++nr) acc[mr][nr] = (f32x4_t){0.f, 0.f, 0.f, 0.f};

  u16x8_t pa[NLA], pb[NLB];
  auto loadAB = [&](int k0) {
    const ushort* ap = A + (size_t)(bm + ra) * K + k0 + ca;
#pragma unroll
    for (int j = 0; j < NLA; ++j) pa[j] = *(const u16x8_t*)(ap + j * 8);
    const ushort* bp = W + (size_t)(bn + rb) * K + k0 + cb;
#pragma unroll
    for (int j = 0; j < NLB; ++j) pb[j] = *(const u16x8_t*)(bp + j * 8);
  };
  auto storeLDS = [&]() {
#pragma unroll
    for (int j = 0; j < NLA; ++j) *(u16x8_t*)&As[ra * SRD + ca + j * 8] = pa[j];
#pragma unroll
    for (int j = 0; j < NLB; ++j) *(u16x8_t*)&Bs[rb * SRD + cb + j * 8] = pb[j];
  };

  loadAB(0);
  storeLDS();
  __syncthreads();

  const int nsteps = K >> 6;
  for (int s = 0; s < nsteps; ++s) {
    const bool more = (s + 1) < nsteps;
    if (more) loadAB((s + 1) << 6);   // prefetch overlaps MFMA

#pragma unroll
    for (int kk = 0; kk < 2; ++kk) {
      bf16x8_t af[MREP];
#pragma unroll
      for (int mr = 0; mr < MREP; ++mr)
        af[mr] = *(const bf16x8_t*)&As[(wr * MREP * 16 + mr * 16 + lr) * SRD + kk * 32 + lg * 8];
#pragma unroll
      for (int nr = 0; nr < NREP; ++nr) {
        const bf16x8_t bf = *(const bf16x8_t*)&Bs[(wc * NREP * 16 + nr * 16 + lr) * SRD + kk * 32 + lg * 8];
#pragma unroll
        for (int mr = 0; mr < MREP; ++mr)
          acc[mr][nr] = __builtin_amdgcn_mfma_f32_16x16x32_bf16(af[mr], bf, acc[mr][nr], 0, 0, 0);
      }
    }
    __syncthreads();
    if (more) { storeLDS(); __syncthreads(); }
  }

  // epilogue: D row = lg*4+v, col = lr (verified mapping)
#pragma unroll
  for (int mr = 0; mr < MREP; ++mr) {
#pragma unroll
    for (int v = 0; v < 4; ++v) {
      const int m = bm + wr * MREP * 16 + mr * 16 + lg * 4 + v;
#pragma unroll
      for (int nr = 0; nr < NREP; ++nr) {
        const int n = bn + wc * NREP * 16 + nr * 16 + lr;
        float val = acc[mr][nr][v] + bias[n];
        if (doRelu) val = fmaxf(val, 0.f);
        if (resid) val += resid[(size_t)m * N + n];
        if (C)  C[(size_t)m * N + n] = val;
        if (Cb) Cb[(size_t)m * N + n] = f2bf(val);
      }
    }
  }
}

// ================= legacy f32 GEMM (embed K=172, fc1, fc2 N=1296) =================
#define GBM 64
#define GBN 64
#define GBK 16
#define LDST 68

__global__ __launch_bounds__(256) void gemm_kernel(
    const float* __restrict__ A, const float* __restrict__ W,
    const float* __restrict__ bias, const float* __restrict__ resid,
    float* __restrict__ C, int M, int N, int K, int doRelu)
{
  __shared__ __align__(16) float As[GBK][LDST];
  __shared__ __align__(16) float Ws[GBK][LDST];
  const int tid = threadIdx.x;
  const int bm = blockIdx.y * GBM;
  const int bn = blockIdx.x * GBN;
  const int tx = tid & 15, ty = tid >> 4;
  const int li = tid >> 2;
  const int lk = (tid & 3) << 2;

  float acc[4][4];
#pragma unroll
  for (int i = 0; i < 4; ++i)
#pragma unroll
    for (int j = 0; j < 4; ++j) acc[i][j] = 0.f;

  for (int k0 = 0; k0 < K; k0 += GBK) {
    float4 av = make_float4(0.f, 0.f, 0.f, 0.f);
    float4 wv = make_float4(0.f, 0.f, 0.f, 0.f);
    {
      const int m = bm + li;
      if (m < M) {
        if (k0 + lk + 4 <= K) {
          av = *(const float4*)&A[(size_t)m * K + k0 + lk];
        } else {
          float t4[4] = {0.f, 0.f, 0.f, 0.f};
          for (int c = 0; c < 4; ++c) { int k = k0 + lk + c; if (k < K) t4[c] = A[(size_t)m * K + k]; }
          av = make_float4(t4[0], t4[1], t4[2], t4[3]);
        }
      }
      const int n = bn + li;
      if (n < N) {
        if (k0 + lk + 4 <= K) {
          wv = *(const float4*)&W[(size_t)n * K + k0 + lk];
        } else {
          float t4[4] = {0.f, 0.f, 0.f, 0.f};
          for (int c = 0; c < 4; ++c) { int k = k0 + lk + c; if (k < K) t4[c] = W[(size_t)n * K + k]; }
          wv = make_float4(t4[0], t4[1], t4[2], t4[3]);
        }
      }
    }
    __syncthreads();
    As[lk + 0][li] = av.x; As[lk + 1][li] = av.y; As[lk + 2][li] = av.z; As[lk + 3][li] = av.w;
    Ws[lk + 0][li] = wv.x; Ws[lk + 1][li] = wv.y; Ws[lk + 2][li] = wv.z; Ws[lk + 3][li] = wv.w;
    __syncthreads();
#pragma unroll
    for (int kk = 0; kk < GBK; ++kk) {
      const float4 a4 = *(const float4*)&As[kk][ty << 2];
      const float4 b4 = *(const float4*)&Ws[kk][tx << 2];
      const float a[4] = {a4.x, a4.y, a4.z, a4.w};
      const float b[4] = {b4.x, b4.y, b4.z, b4.w};
#pragma unroll
      for (int i = 0; i < 4; ++i)
#pragma unroll
        for (int j = 0; j < 4; ++j) acc[i][j] = fmaf(a[i], b[j], acc[i][j]);
    }
  }

#pragma unroll
  for (int i = 0; i < 4; ++i) {
    const int m = bm + (ty << 2) + i;
    if (m >= M) continue;
#pragma unroll
    for (int j = 0; j < 4; ++j) {
      const int n = bn + (tx << 2) + j;
      if (n >= N) continue;
      float v = acc[i][j] + bias[n];
      if (doRelu) v = fmaxf(v, 0.f);
      if (resid) v += resid[(size_t)m * N + n];
      C[(size_t)m * N + n] = v;
    }
  }
}

// ---------- LayerNorm (f32 in-place + bf16 copy) ----------
__global__ __launch_bounds__(256) void ln_kernel(
    float* __restrict__ X, ushort* __restrict__ Xb,
    const float* __restrict__ g, const float* __restrict__ bta)
{
  const int row = blockIdx.x;
  const int tid = threadIdx.x;
  float* xr = X + (size_t)row * kD;
  const float x0 = xr[tid];
  const float x1 = xr[tid + 256];
  float s = x0 + x1;
  float q = x0 * x0 + x1 * x1;
#pragma unroll
  for (int off = 32; off > 0; off >>= 1) {
    s += __shfl_down(s, off);
    q += __shfl_down(q, off);
  }
  __shared__ float ss[4], qq[4];
  const int w = tid >> 6;
  if ((tid & 63) == 0) { ss[w] = s; qq[w] = q; }
  __syncthreads();
  const float S = ss[0] + ss[1] + ss[2] + ss[3];
  const float Q = qq[0] + qq[1] + qq[2] + qq[3];
  const float mean = S * (1.f / kD);
  const float var = Q * (1.f / kD) - mean * mean;
  const float inv = rsqrtf(var + kEps);
  const float v0 = (x0 - mean) * inv * g[tid] + bta[tid];
  const float v1 = (x1 - mean) * inv * g[tid + 256] + bta[tid + 256];
  xr[tid] = v0; xr[tid + 256] = v1;
  ushort* xb = Xb + (size_t)row * kD;
  xb[tid] = f2bf(v0); xb[tid + 256] = f2bf(v1);
}

// ---------- MFMA flash attention (bf16 qkv in, bf16 out, f32 softmax/accum) ----------
#define KSTR 72
__global__ __launch_bounds__(256) void attn_mfma_kernel(
    const ushort* __restrict__ qkv, ushort* __restrict__ O)
{
  const int b = blockIdx.z, h = blockIdx.y;
  const int q0 = blockIdx.x << 6;
  const int tid = threadIdx.x;
  const int wv = tid >> 6, lane = tid & 63;
  const int lr = lane & 15;
  const int lg = lane >> 4;

  __shared__ ushort Ks[64 * KSTR];
  __shared__ ushort Vt[64 * KSTR];
  __shared__ ushort Pl[4][16 * KSTR];

  bf16x8_t qa[2];
  {
    const ushort* qrow = qkv + ((size_t)(b * kT + q0 + wv * 16 + lr)) * (3 * kD) + h * kHD + lg * 8;
    qa[0] = *(const bf16x8_t*)qrow;
    qa[1] = *(const bf16x8_t*)(qrow + 32);
  }

  float m_[4], l_[4];
  f32x4_t oacc[4];
#pragma unroll
  for (int r = 0; r < 4; ++r) { m_[r] = -1e30f; l_[r] = 0.f; }
#pragma unroll
  for (int nb = 0; nb < 4; ++nb) oacc[nb] = (f32x4_t){0.f, 0.f, 0.f, 0.f};

  const int srow = tid >> 2;
  const int sd   = (tid & 3) << 4;

  for (int kt = 0; kt < kT / 64; ++kt) {
    __syncthreads();
    {
      const ushort* kr = qkv + ((size_t)(b * kT + (kt << 6) + srow)) * (3 * kD) + kD + h * kHD + sd;
      *(u16x8_t*)&Ks[srow * KSTR + sd]     = *(const u16x8_t*)kr;
      *(u16x8_t*)&Ks[srow * KSTR + sd + 8] = *(const u16x8_t*)(kr + 8);
      const ushort* vr = kr + kD;
      const u16x8_t v0 = *(const u16x8_t*)vr;
      const u16x8_t v1 = *(const u16x8_t*)(vr + 8);
#pragma unroll
      for (int e = 0; e < 8; ++e) {
        Vt[(sd + e) * KSTR + srow] = v0[e];
        Vt[(sd + 8 + e) * KSTR + srow] = v1[e];
      }
    }
    __syncthreads();

    f32x4_t s[4];
#pragma unroll
    for (int cc = 0; cc < 4; ++cc) {
      const ushort* kb = &Ks[(cc * 16 + lr) * KSTR + lg * 8];
      const bf16x8_t k0 = *(const bf16x8_t*)kb;
      const bf16x8_t k1 = *(const bf16x8_t*)(kb + 32);
      f32x4_t acc = (f32x4_t){0.f, 0.f, 0.f, 0.f};
      acc = __builtin_amdgcn_mfma_f32_16x16x32_bf16(qa[0], k0, acc, 0, 0, 0);
      acc = __builtin_amdgcn_mfma_f32_16x16x32_bf16(qa[1], k1, acc, 0, 0, 0);
#pragma unroll
      for (int r = 0; r < 4; ++r) acc[r] *= 0.125f;
      s[cc] = acc;
    }

#pragma unroll
    for (int r = 0; r < 4; ++r) {
      float mx = fmaxf(fmaxf(s[0][r], s[1][r]), fmaxf(s[2][r], s[3][r]));
      mx = fmaxf(mx, __shfl_xor(mx, 1));
      mx = fmaxf(mx, __shfl_xor(mx, 2));
      mx = fmaxf(mx, __shfl_xor(mx, 4));
      mx = fmaxf(mx, __shfl_xor(mx, 8));
      const float mnew = fmaxf(m_[r], mx);
      const float alpha = __expf(m_[r] - mnew);
      float sum = 0.f;
#pragma unroll
      for (int cc = 0; cc < 4; ++cc) {
        const float p = __expf(s[cc][r] - mnew);
        s[cc][r] = p;
        sum += p;
      }
      sum += __shfl_xor(sum, 1);
      sum += __shfl_xor(sum, 2);
      sum += __shfl_xor(sum, 4);
      sum += __shfl_xor(sum, 8);
      l_[r] = l_[r] * alpha + sum;
      m_[r] = mnew;
#pragma unroll
      for (int nb = 0; nb < 4; ++nb) oacc[nb][r] *= alpha;
#pragma unroll
      for (int cc = 0; cc < 4; ++cc)
        Pl[wv][(lg * 4 + r) * KSTR + cc * 16 + lr] = f2bf(s[cc][r]);
    }

    const bf16x8_t pa0 = *(const bf16x8_t*)&Pl[wv][lr * KSTR + lg * 8];
    const bf16x8_t pa1 = *(const bf16x8_t*)&Pl[wv][lr * KSTR + 32 + lg * 8];
#pragma unroll
    for (int nb = 0; nb < 4; ++nb) {
      const ushort* vb = &Vt[(nb * 16 + lr) * KSTR + lg * 8];
      const bf16x8_t v0 = *(const bf16x8_t*)vb;
      const bf16x8_t v1 = *(const bf16x8_t*)(vb + 32);
      oacc[nb] = __builtin_amdgcn_mfma_f32_16x16x32_bf16(pa0, v0, oacc[nb], 0, 0, 0);
      oacc[nb] = __builtin_amdgcn_mfma_f32_16x16x32_bf16(pa1, v1, oacc[nb], 0, 0, 0);
    }
  }

#pragma unroll
  for (int nb = 0; nb < 4; ++nb) {
#pragma unroll
    for (int r = 0; r < 4; ++r) {
      const int row = lg * 4 + r;
      const int col = nb * 16 + lr;
      O[((size_t)(b * kT + q0 + wv * 16 + row)) * kD + h * kHD + col] = f2bf(oacc[nb][r] / l_[r]);
    }
  }
}

// ---------- positional encoding add (f32 + bf16 copy) ----------
__global__ __launch_bounds__(256) void posenc_kernel(float* __restrict__ X, ushort* __restrict__ Xb)
{
  const int bt = blockIdx.x;
  const int t = bt & (kT - 1);
  float* row = X + (size_t)bt * kD;
  ushort* rb = Xb + (size_t)bt * kD;
#pragma unroll
  for (int p = 0; p < 2; ++p) {
    const int d = threadIdx.x + p * 256;
    const int j = d >> 1;
    const float inv = expf(-(float)j * 0.03597789207803197f);  // ln(10000)/256
    const float ang = (float)t * inv;
    const float pe = (d & 1) ? cosf(ang) : sinf(ang);
    const float v = row[d] + pe;
    row[d] = v;
    rb[d] = f2bf(v);
  }
}

// ---------- fused avgpool + im2col (bf16 out) ----------
__global__ void im2col_pool_kernel(const float* __restrict__ X, ushort* __restrict__ X5,
                                   int Tt, int n4)
{
  const int idx = blockIdx.x * 256 + threadIdx.x;
  if (idx >= n4) return;
  const int ci4 = idx & 127;
  int r = idx >> 7;
  const int tap = r % 5; r /= 5;
  const int t = r % Tt;
  const int b = r / Tt;
  const int ts = t + tap - 2;
  u16x4_t o = (u16x4_t){0, 0, 0, 0};
  if (ts >= 0 && ts < Tt) {
    const float* p = X + ((size_t)(b * 2 * Tt + 2 * ts)) * kD + ci4 * 4;
    const float4 x0 = *(const float4*)p;
    const float4 x1 = *(const float4*)(p + kD);
    o[0] = f2bf(0.5f * (x0.x + x1.x)); o[1] = f2bf(0.5f * (x0.y + x1.y));
    o[2] = f2bf(0.5f * (x0.z + x1.z)); o[3] = f2bf(0.5f * (x0.w + x1.w));
  }
  *(u16x4_t*)&X5[((size_t)(b * Tt + t)) * 2560 + tap * kD + ci4 * 4] = o;
}

// conv weight transpose -> bf16: Wt[co][tap*512+ci] = w[co][ci][tap]
__global__ void convw_t_kernel(const float* __restrict__ w, ushort* __restrict__ Wt)
{
  const int idx = blockIdx.x * 256 + threadIdx.x;
  if (idx >= 512 * 512 * 5) return;
  const int ci = idx & 511;
  int r = idx >> 9;
  const int tap = r % 5;
  const int co = r / 5;
  Wt[(size_t)co * 2560 + tap * 512 + ci] = f2bf(w[(size_t)co * 2560 + ci * 5 + tap]);
}

// ---------- small elementwise kernels ----------
__global__ void copy_kernel(const float* __restrict__ X, float* __restrict__ Y2, int n)
{
  const int i = blockIdx.x * 256 + threadIdx.x;
  if (i < n) Y2[i] = X[i];
}
__global__ void add_dual_kernel(float* __restrict__ A, ushort* __restrict__ Ab,
                                const float* __restrict__ P, int n)
{
  const int i = blockIdx.x * 256 + threadIdx.x;
  if (i >= n) return;
  const float v = A[i] + P[i];
  A[i] = v;
  Ab[i] = f2bf(v);
}

extern "C" void kernel_launch(void* const* d_in, const int* in_sizes, int n_in,
                              void* d_out, int out_size, void* d_ws, size_t ws_size,
                              hipStream_t stream)
{
  (void)in_sizes; (void)n_in; (void)out_size;
  const float* poses  = (const float*)d_in[0];
  const float* pose_w = (const float*)d_in[1];
  const float* pose_b = (const float*)d_in[2];
  const float* in_w   = (const float*)d_in[3];
  const float* in_b   = (const float*)d_in[4];
  const float* out_w  = (const float*)d_in[5];
  const float* out_b  = (const float*)d_in[6];
  const float* ln1_g  = (const float*)d_in[7];
  const float* ln1_b  = (const float*)d_in[8];
  const float* ffn_w1 = (const float*)d_in[9];
  const float* ffn_b1 = (const float*)d_in[10];
  const float* ffn_w2 = (const float*)d_in[11];
  const float* ffn_b2 = (const float*)d_in[12];
  const float* ln2_g  = (const float*)d_in[13];
  const float* ln2_b  = (const float*)d_in[14];
  const float* tcn1_w = (const float*)d_in[15];
  const float* tcn1_b = (const float*)d_in[16];
  const float* tcn2_w = (const float*)d_in[17];
  const float* tcn2_b = (const float*)d_in[18];
  const float* fc1_w  = (const float*)d_in[19];
  const float* fc1_b  = (const float*)d_in[20];
  const float* fc2_w  = (const float*)d_in[21];
  const float* fc2_b  = (const float*)d_in[22];

  // ---- workspace layout (byte offsets) ----
  // f32:  A 8MB | Y 8MB | P 8MB
  // bf16: Abf 4MB | QKV 12MB (alias: Ybf, X5) | MID 16MB (alias: ATTbf, CW) | W ...
  char* base = (char*)d_ws;
  const size_t SZ = (size_t)kB * kT * kD;      // 2,097,152 elems
  float*  A    = (float*)(base);
  float*  Y    = (float*)(base + 8388608);
  float*  P    = (float*)(base + 16777216);
  ushort* Abf  = (ushort*)(base + 25165824);
  ushort* QKV  = (ushort*)(base + 29360128);   // 6M ushort
  ushort* Ybf  = QKV;                          // lifetime-disjoint alias
  ushort* X5   = QKV;                          // head phase
  ushort* MID  = (ushort*)(base + 41943040);   // 8M ushort
  ushort* ATTb = MID;                          // lifetime-disjoint alias
  ushort* CW   = MID;                          // head phase
  ushort* Wbf  = (ushort*)(base + 58720256);

  // per-layer weight element counts
  const size_t nWq = (size_t)3 * kD * kD;      // 786432
  const size_t nWo = (size_t)kD * kD;          // 262144
  const size_t nW1 = (size_t)kFF * kD;         // 1048576
  const size_t nW2 = (size_t)kD * kFF;         // 1048576
  const size_t nWl = nWq + nWo + nW1 + nW2;    // 3145728
  const bool fullW = ws_size >= (size_t)58720256 + nWl * 8 * 2;

  const int M = kB * kT;  // 4096
  dim3 blk(256);
  auto cvt = [&](const float* s, ushort* d, size_t n) {
    cvt_kernel<<<(int)((n / 8 + 255) / 256), blk, 0, stream>>>(s, d, (int)(n / 8));
  };

  if (fullW) {   // one-time per launch: convert all transformer weights
    cvt(in_w,   Wbf,                        nWq * 8);
    cvt(out_w,  Wbf + nWq * 8,              nWo * 8);
    cvt(ffn_w1, Wbf + nWq * 8 + nWo * 8,    nW1 * 8);
    cvt(ffn_w2, Wbf + (nWq + nWo + nW1) * 8, nW2 * 8);
  }

  // embed: A = poses @ pose_w.T + pose_b ; += posenc (writes A + Abf)
  gemm_kernel<<<dim3(kD / GBN, M / GBM), blk, 0, stream>>>(poses, pose_w, pose_b, nullptr, A, M, kD, kIn, 0);
  posenc_kernel<<<M, blk, 0, stream>>>(A, Abf);

  for (int l = 0; l < 8; ++l) {
    const ushort *Wq, *Wo, *W1, *W2;
    if (fullW) {
      Wq = Wbf + (size_t)l * nWq;
      Wo = Wbf + nWq * 8 + (size_t)l * nWo;
      W1 = Wbf + nWq * 8 + nWo * 8 + (size_t)l * nW1;
      W2 = Wbf + (nWq + nWo + nW1) * 8 + (size_t)l * nW2;
    } else {   // rotate: convert this layer's weights into Wbf
      cvt(in_w   + (size_t)l * nWq, Wbf, nWq);
      cvt(out_w  + (size_t)l * nWo, Wbf + nWq, nWo);
      cvt(ffn_w1 + (size_t)l * nW1, Wbf + nWq + nWo, nW1);
      cvt(ffn_w2 + (size_t)l * nW2, Wbf + nWq + nWo + nW1, nW2);
      Wq = Wbf; Wo = Wbf + nWq; W1 = Wbf + nWq + nWo; W2 = Wbf + nWq + nWo + nW1;
    }

    if (l == 2 || l == 4 || l == 6)
      copy_kernel<<<(int)(SZ / 256), blk, 0, stream>>>(A, P, (int)SZ);

    // qkv (bf16 out only)
    bgemm_kernel<4, 4><<<dim3(3 * kD / 128, M / 128), blk, 0, stream>>>(
        Abf, Wq, in_b + (size_t)l * 3 * kD, nullptr, nullptr, QKV, M, 3 * kD, kD, 0);
    // attention (bf16 in/out)
    attn_mfma_kernel<<<dim3(kT / 64, kH, kB), blk, 0, stream>>>(QKV, ATTb);
    // out-proj: Y = ATTb @ Wo + b + A (f32 out)
    bgemm_kernel<2, 4><<<dim3(kD / 128, M / 64), blk, 0, stream>>>(
        ATTb, Wo, out_b + (size_t)l * kD, A, Y, nullptr, M, kD, kD, 0);
    ln_kernel<<<M, blk, 0, stream>>>(Y, Ybf, ln1_g + (size_t)l * kD, ln1_b + (size_t)l * kD);
    // ffn1: MID = relu(Ybf @ W1 + b)  (bf16 out only)
    bgemm_kernel<4, 4><<<dim3(kFF / 128, M / 128), blk, 0, stream>>>(
        Ybf, W1, ffn_b1 + (size_t)l * kFF, nullptr, nullptr, MID, M, kFF, kD, 1);
    // ffn2: A = MID @ W2 + b + Y (f32 out)
    bgemm_kernel<2, 4><<<dim3(kD / 128, M / 64), blk, 0, stream>>>(
        MID, W2, ffn_b2 + (size_t)l * kD, Y, A, nullptr, M, kD, kFF, 0);
    ln_kernel<<<M, blk, 0, stream>>>(A, Abf, ln2_g + (size_t)l * kD, ln2_b + (size_t)l * kD);

    if (l == 3 || l == 5 || l == 7)
      add_dual_kernel<<<(int)(SZ / 256), blk, 0, stream>>>(A, Abf, P, (int)SZ);
  }

  // head: pool+conv1 -> pool+conv2 -> fc1 -> fc2
  {
    const int T1 = kT / 2;   // 512
    const int T2 = kT / 4;   // 256
    convw_t_kernel<<<(512 * 512 * 5 + 255) / 256, blk, 0, stream>>>(tcn1_w, CW);
    const int n4a = kB * T1 * 5 * (kD / 4);
    im2col_pool_kernel<<<(n4a + 255) / 256, blk, 0, stream>>>(A, X5, T1, n4a);
    bgemm_kernel<2, 2><<<dim3(kD / 64, kB * T1 / 64), blk, 0, stream>>>(
        X5, CW, tcn1_b, nullptr, Y, nullptr, kB * T1, kD, 2560, 0);
    convw_t_kernel<<<(512 * 512 * 5 + 255) / 256, blk, 0, stream>>>(tcn2_w, CW);
    const int n4b = kB * T2 * 5 * (kD / 4);
    im2col_pool_kernel<<<(n4b + 255) / 256, blk, 0, stream>>>(Y, X5, T2, n4b);
    bgemm_kernel<2, 2><<<dim3(kD / 64, kB * T2 / 64), blk, 0, stream>>>(
        X5, CW, tcn2_b, nullptr, A, nullptr, kB * T2, kD, 2560, 0);
    const int Mh = kB * T2;  // 1024
    gemm_kernel<<<dim3(128 / GBN, Mh / GBM), blk, 0, stream>>>(A, fc1_w, fc1_b, nullptr, Y, Mh, 128, kD, 0);
    gemm_kernel<<<dim3((kNCLS + GBN - 1) / GBN, Mh / GBM), blk, 0, stream>>>(
        Y, fc2_w, fc2_b, nullptr, (float*)d_out, Mh, kNCLS, 128, 0);
  }
}

// Round 7
// 1457.609 us; speedup vs baseline: 5.9000x; 1.0288x over previous
//
#include <hip/hip_runtime.h>
#include <hip/hip_bf16.h>

static constexpr int kB = 4;
static constexpr int kT = 1024;
static constexpr int kIn = 172;
static constexpr int kD = 512;
static constexpr int kH = 8;
static constexpr int kHD = 64;
static constexpr int kFF = 2048;
static constexpr int kNCLS = 1296;
static constexpr float kEps = 1e-5f;

typedef __attribute__((ext_vector_type(8))) short bf16x8_t;
typedef __attribute__((ext_vector_type(4))) float f32x4_t;
typedef __attribute__((ext_vector_type(8))) unsigned short u16x8_t;
typedef __attribute__((ext_vector_type(4))) unsigned short u16x4_t;

// round-to-nearest-even f32 -> bf16 bits (finite inputs)
static __device__ __forceinline__ unsigned short f2bf(float f) {
  unsigned int u = __float_as_uint(f);
  unsigned int r = (u + 0x7fffu + ((u >> 16) & 1u)) >> 16;
  return (unsigned short)r;
}

// ---------- f32 -> bf16 bulk convert (n % 8 == 0) ----------
__global__ void cvt_kernel(const float* __restrict__ src, ushort* __restrict__ dst, int n8)
{
  const int i = blockIdx.x * 256 + threadIdx.x;
  if (i >= n8) return;
  const float4 a = *(const float4*)&src[i * 8];
  const float4 b = *(const float4*)&src[i * 8 + 4];
  u16x8_t t;
  t[0] = f2bf(a.x); t[1] = f2bf(a.y); t[2] = f2bf(a.z); t[3] = f2bf(a.w);
  t[4] = f2bf(b.x); t[5] = f2bf(b.y); t[6] = f2bf(b.z); t[7] = f2bf(b.w);
  *(u16x8_t*)&dst[i * 8] = t;
}

// ================= bf16 MFMA GEMM =================
// C[m,n] = sum_k A[m,k]*W[n,k] + bias[n] (+relu) (+resid f32); C f32 and/or Cb bf16.
// BM=MREP*32, BN=NREP*32, BK=64. 256 threads = 4 waves (2Mx2N).
// Requires M%BM==0, N%BN==0, K%64==0.
template<int MREP, int NREP>
__global__ __launch_bounds__(256) void bgemm_kernel(
    const ushort* __restrict__ A, const ushort* __restrict__ W,
    const float* __restrict__ bias, const float* __restrict__ resid,
    float* __restrict__ C, ushort* __restrict__ Cb, int M, int N, int K, int doRelu)
{
  constexpr int BM = MREP * 32, BN = NREP * 32;
  constexpr int SRD = 72;              // ushort row stride (144 B) -> 2-way banks (free)
  constexpr int TPRA = 256 / BM, CSA = 64 / TPRA, NLA = CSA / 8;
  constexpr int TPRB = 256 / BN, CSB = 64 / TPRB, NLB = CSB / 8;
  __shared__ ushort As[BM * SRD];
  __shared__ ushort Bs[BN * SRD];

  const int tid = threadIdx.x;
  // XCD-aware swizzle (grids here are all %8==0, guarded anyway)
  int bid = blockIdx.y * gridDim.x + blockIdx.x;
  const int nwg = gridDim.x * gridDim.y;
  if ((nwg & 7) == 0) bid = (bid & 7) * (nwg >> 3) + (bid >> 3);
  const int bm = (bid / gridDim.x) * BM, bn = (bid % gridDim.x) * BN;

  const int wv = tid >> 6, lane = tid & 63;
  const int lr = lane & 15, lg = lane >> 4;
  const int wr = wv >> 1, wc = wv & 1;

  const int ra = tid / TPRA, ca = (tid % TPRA) * CSA;
  const int rb = tid / TPRB, cb = (tid % TPRB) * CSB;

  f32x4_t acc[MREP][NREP];
#pragma unroll
  for (int mr = 0; mr < MREP; ++mr)
#pragma unroll
    for (int nr = 0; nr < NREP; ++nr) acc[mr][nr] = (f32x4_t){0.f, 0.f, 0.f, 0.f};

  u16x8_t pa[NLA], pb[NLB];
  auto loadAB = [&](int k0) {
    const ushort* ap = A + (size_t)(bm + ra) * K + k0 + ca;
#pragma unroll
    for (int j = 0; j < NLA; ++j) pa[j] = *(const u16x8_t*)(ap + j * 8);
    const ushort* bp = W + (size_t)(bn + rb) * K + k0 + cb;
#pragma unroll
    for (int j = 0; j < NLB; ++j) pb[j] = *(const u16x8_t*)(bp + j * 8);
  };
  auto storeLDS = [&]() {
#pragma unroll
    for (int j = 0; j < NLA; ++j) *(u16x8_t*)&As[ra * SRD + ca + j * 8] = pa[j];
#pragma unroll
    for (int j = 0; j < NLB; ++j) *(u16x8_t*)&Bs[rb * SRD + cb + j * 8] = pb[j];
  };

  loadAB(0);
  storeLDS();
  __syncthreads();

  const int nsteps = K >> 6;
  for (int s = 0; s < nsteps; ++s) {
    const bool more = (s + 1) < nsteps;
    if (more) loadAB((s + 1) << 6);   // prefetch overlaps MFMA

#pragma unroll
    for (int kk = 0; kk < 2; ++kk) {
      bf16x8_t af[MREP];
#pragma unroll
      for (int mr = 0; mr < MREP; ++mr)
        af[mr] = *(const bf16x8_t*)&As[(wr * MREP * 16 + mr * 16 + lr) * SRD + kk * 32 + lg * 8];
#pragma unroll
      for (int nr = 0; nr < NREP; ++nr) {
        const bf16x8_t bf = *(const bf16x8_t*)&Bs[(wc * NREP * 16 + nr * 16 + lr) * SRD + kk * 32 + lg * 8];
#pragma unroll
        for (int mr = 0; mr < MREP; ++mr)
          acc[mr][nr] = __builtin_amdgcn_mfma_f32_16x16x32_bf16(af[mr], bf, acc[mr][nr], 0, 0, 0);
      }
    }
    __syncthreads();
    if (more) { storeLDS(); __syncthreads(); }
  }

  // epilogue: D row = lg*4+v, col = lr (verified mapping)
#pragma unroll
  for (int mr = 0; mr < MREP; ++mr) {
#pragma unroll
    for (int v = 0; v < 4; ++v) {
      const int m = bm + wr * MREP * 16 + mr * 16 + lg * 4 + v;
#pragma unroll
      for (int nr = 0; nr < NREP; ++nr) {
        const int n = bn + wc * NREP * 16 + nr * 16 + lr;
        float val = acc[mr][nr][v] + bias[n];
        if (doRelu) val = fmaxf(val, 0.f);
        if (resid) val += resid[(size_t)m * N + n];
        if (C)  C[(size_t)m * N + n] = val;
        if (Cb) Cb[(size_t)m * N + n] = f2bf(val);
      }
    }
  }
}

// ================= legacy f32 GEMM (embed K=172, fc1, fc2 N=1296) =================
#define GBM 64
#define GBN 64
#define GBK 16
#define LDST 68

__global__ __launch_bounds__(256) void gemm_kernel(
    const float* __restrict__ A, const float* __restrict__ W,
    const float* __restrict__ bias, const float* __restrict__ resid,
    float* __restrict__ C, int M, int N, int K, int doRelu)
{
  __shared__ __align__(16) float As[GBK][LDST];
  __shared__ __align__(16) float Ws[GBK][LDST];
  const int tid = threadIdx.x;
  const int bm = blockIdx.y * GBM;
  const int bn = blockIdx.x * GBN;
  const int tx = tid & 15, ty = tid >> 4;
  const int li = tid >> 2;
  const int lk = (tid & 3) << 2;

  float acc[4][4];
#pragma unroll
  for (int i = 0; i < 4; ++i)
#pragma unroll
    for (int j = 0; j < 4; ++j) acc[i][j] = 0.f;

  for (int k0 = 0; k0 < K; k0 += GBK) {
    float4 av = make_float4(0.f, 0.f, 0.f, 0.f);
    float4 wv = make_float4(0.f, 0.f, 0.f, 0.f);
    {
      const int m = bm + li;
      if (m < M) {
        if (k0 + lk + 4 <= K) {
          av = *(const float4*)&A[(size_t)m * K + k0 + lk];
        } else {
          float t4[4] = {0.f, 0.f, 0.f, 0.f};
          for (int c = 0; c < 4; ++c) { int k = k0 + lk + c; if (k < K) t4[c] = A[(size_t)m * K + k]; }
          av = make_float4(t4[0], t4[1], t4[2], t4[3]);
        }
      }
      const int n = bn + li;
      if (n < N) {
        if (k0 + lk + 4 <= K) {
          wv = *(const float4*)&W[(size_t)n * K + k0 + lk];
        } else {
          float t4[4] = {0.f, 0.f, 0.f, 0.f};
          for (int c = 0; c < 4; ++c) { int k = k0 + lk + c; if (k < K) t4[c] = W[(size_t)n * K + k]; }
          wv = make_float4(t4[0], t4[1], t4[2], t4[3]);
        }
      }
    }
    __syncthreads();
    As[lk + 0][li] = av.x; As[lk + 1][li] = av.y; As[lk + 2][li] = av.z; As[lk + 3][li] = av.w;
    Ws[lk + 0][li] = wv.x; Ws[lk + 1][li] = wv.y; Ws[lk + 2][li] = wv.z; Ws[lk + 3][li] = wv.w;
    __syncthreads();
#pragma unroll
    for (int kk = 0; kk < GBK; ++kk) {
      const float4 a4 = *(const float4*)&As[kk][ty << 2];
      const float4 b4 = *(const float4*)&Ws[kk][tx << 2];
      const float a[4] = {a4.x, a4.y, a4.z, a4.w};
      const float b[4] = {b4.x, b4.y, b4.z, b4.w};
#pragma unroll
      for (int i = 0; i < 4; ++i)
#pragma unroll
        for (int j = 0; j < 4; ++j) acc[i][j] = fmaf(a[i], b[j], acc[i][j]);
    }
  }

#pragma unroll
  for (int i = 0; i < 4; ++i) {
    const int m = bm + (ty << 2) + i;
    if (m >= M) continue;
#pragma unroll
    for (int j = 0; j < 4; ++j) {
      const int n = bn + (tx << 2) + j;
      if (n >= N) continue;
      float v = acc[i][j] + bias[n];
      if (doRelu) v = fmaxf(v, 0.f);
      if (resid) v += resid[(size_t)m * N + n];
      C[(size_t)m * N + n] = v;
    }
  }
}

// ---------- LayerNorm (f32 in-place + bf16 copy, optional skip-add/skip-save) ----------
// v = ln(x)*g + b (+ Padd[row]);  X=v, Xb=bf16(v), (Pout=v)
__global__ __launch_bounds__(256) void ln_kernel(
    float* __restrict__ X, ushort* __restrict__ Xb,
    const float* __restrict__ g, const float* __restrict__ bta,
    const float* Padd, float* Pout)
{
  const int row = blockIdx.x;
  const int tid = threadIdx.x;
  float* xr = X + (size_t)row * kD;
  const float x0 = xr[tid];
  const float x1 = xr[tid + 256];
  float s = x0 + x1;
  float q = x0 * x0 + x1 * x1;
#pragma unroll
  for (int off = 32; off > 0; off >>= 1) {
    s += __shfl_down(s, off);
    q += __shfl_down(q, off);
  }
  __shared__ float ss[4], qq[4];
  const int w = tid >> 6;
  if ((tid & 63) == 0) { ss[w] = s; qq[w] = q; }
  __syncthreads();
  const float S = ss[0] + ss[1] + ss[2] + ss[3];
  const float Q = qq[0] + qq[1] + qq[2] + qq[3];
  const float mean = S * (1.f / kD);
  const float var = Q * (1.f / kD) - mean * mean;
  const float inv = rsqrtf(var + kEps);
  float v0 = (x0 - mean) * inv * g[tid] + bta[tid];
  float v1 = (x1 - mean) * inv * g[tid + 256] + bta[tid + 256];
  if (Padd) {
    v0 += Padd[(size_t)row * kD + tid];
    v1 += Padd[(size_t)row * kD + tid + 256];
  }
  xr[tid] = v0; xr[tid + 256] = v1;
  ushort* xb = Xb + (size_t)row * kD;
  xb[tid] = f2bf(v0); xb[tid + 256] = f2bf(v1);
  if (Pout) {
    Pout[(size_t)row * kD + tid] = v0;
    Pout[(size_t)row * kD + tid + 256] = v1;
  }
}

// ---------- MFMA flash attention (bf16 qkv in, bf16 out, f32 softmax/accum) ----------
#define KSTR 72   // K/V LDS row stride (ushort)
#define PSTR 74   // P LDS row stride (odd dword stride 37 -> ~2-way write banks)
__global__ __launch_bounds__(256) void attn_mfma_kernel(
    const ushort* __restrict__ qkv, ushort* __restrict__ O)
{
  const int b = blockIdx.z, h = blockIdx.y;
  const int q0 = blockIdx.x << 6;
  const int tid = threadIdx.x;
  const int wv = tid >> 6, lane = tid & 63;
  const int lr = lane & 15;
  const int lg = lane >> 4;

  __shared__ ushort Ks[64 * KSTR];
  __shared__ ushort Vt[64 * KSTR];
  __shared__ ushort Pl[4][16 * PSTR];

  bf16x8_t qa[2];
  {
    const ushort* qrow = qkv + ((size_t)(b * kT + q0 + wv * 16 + lr)) * (3 * kD) + h * kHD + lg * 8;
    qa[0] = *(const bf16x8_t*)qrow;
    qa[1] = *(const bf16x8_t*)(qrow + 32);
  }

  float m_[4], l_[4];
  f32x4_t oacc[4];
#pragma unroll
  for (int r = 0; r < 4; ++r) { m_[r] = -1e30f; l_[r] = 0.f; }
#pragma unroll
  for (int nb = 0; nb < 4; ++nb) oacc[nb] = (f32x4_t){0.f, 0.f, 0.f, 0.f};

  const int srow = tid >> 2;          // K staging: key row 0..63
  const int sd   = (tid & 3) << 4;    // K staging: d offset 0,16,32,48
  const int vkp  = tid & 31;          // V staging: key pair (keys 2vkp, 2vkp+1)
  const int vdh  = tid >> 5;          // V staging: d octet (d = vdh*8 .. +8)

  for (int kt = 0; kt < kT / 64; ++kt) {
    __syncthreads();
    {
      // K: row-major, 16B vector stores (≈free banks)
      const ushort* kr = qkv + ((size_t)(b * kT + (kt << 6) + srow)) * (3 * kD) + kD + h * kHD + sd;
      *(u16x8_t*)&Ks[srow * KSTR + sd]     = *(const u16x8_t*)kr;
      *(u16x8_t*)&Ks[srow * KSTR + sd + 8] = *(const u16x8_t*)(kr + 8);
      // V: transposed via key-pair dword packing -> bank (4e+kp)%32, 2-way (free)
      const ushort* vr = qkv + ((size_t)(b * kT + (kt << 6) + 2 * vkp)) * (3 * kD) + 2 * kD + h * kHD + vdh * 8;
      const u16x8_t v0 = *(const u16x8_t*)vr;
      const u16x8_t v1 = *(const u16x8_t*)(vr + 3 * kD);
#pragma unroll
      for (int e = 0; e < 8; ++e) {
        const unsigned int packv = (unsigned int)v0[e] | ((unsigned int)v1[e] << 16);
        *(unsigned int*)&Vt[(vdh * 8 + e) * KSTR + 2 * vkp] = packv;
      }
    }
    __syncthreads();

    f32x4_t s[4];
#pragma unroll
    for (int cc = 0; cc < 4; ++cc) {
      const ushort* kb = &Ks[(cc * 16 + lr) * KSTR + lg * 8];
      const bf16x8_t k0 = *(const bf16x8_t*)kb;
      const bf16x8_t k1 = *(const bf16x8_t*)(kb + 32);
      f32x4_t acc = (f32x4_t){0.f, 0.f, 0.f, 0.f};
      acc = __builtin_amdgcn_mfma_f32_16x16x32_bf16(qa[0], k0, acc, 0, 0, 0);
      acc = __builtin_amdgcn_mfma_f32_16x16x32_bf16(qa[1], k1, acc, 0, 0, 0);
#pragma unroll
      for (int r = 0; r < 4; ++r) acc[r] *= 0.125f;
      s[cc] = acc;
    }

#pragma unroll
    for (int r = 0; r < 4; ++r) {
      float mx = fmaxf(fmaxf(s[0][r], s[1][r]), fmaxf(s[2][r], s[3][r]));
      mx = fmaxf(mx, __shfl_xor(mx, 1));
      mx = fmaxf(mx, __shfl_xor(mx, 2));
      mx = fmaxf(mx, __shfl_xor(mx, 4));
      mx = fmaxf(mx, __shfl_xor(mx, 8));
      const float mnew = fmaxf(m_[r], mx);
      const float alpha = __expf(m_[r] - mnew);
      float sum = 0.f;
#pragma unroll
      for (int cc = 0; cc < 4; ++cc) {
        const float p = __expf(s[cc][r] - mnew);
        s[cc][r] = p;
        sum += p;
      }
      sum += __shfl_xor(sum, 1);
      sum += __shfl_xor(sum, 2);
      sum += __shfl_xor(sum, 4);
      sum += __shfl_xor(sum, 8);
      l_[r] = l_[r] * alpha + sum;
      m_[r] = mnew;
#pragma unroll
      for (int nb = 0; nb < 4; ++nb) oacc[nb][r] *= alpha;
#pragma unroll
      for (int cc = 0; cc < 4; ++cc)
        Pl[wv][(lg * 4 + r) * PSTR + cc * 16 + lr] = f2bf(s[cc][r]);
    }

    const bf16x8_t pa0 = *(const bf16x8_t*)&Pl[wv][lr * PSTR + lg * 8];
    const bf16x8_t pa1 = *(const bf16x8_t*)&Pl[wv][lr * PSTR + 32 + lg * 8];
#pragma unroll
    for (int nb = 0; nb < 4; ++nb) {
      const ushort* vb = &Vt[(nb * 16 + lr) * KSTR + lg * 8];
      const bf16x8_t v0 = *(const bf16x8_t*)vb;
      const bf16x8_t v1 = *(const bf16x8_t*)(vb + 32);
      oacc[nb] = __builtin_amdgcn_mfma_f32_16x16x32_bf16(pa0, v0, oacc[nb], 0, 0, 0);
      oacc[nb] = __builtin_amdgcn_mfma_f32_16x16x32_bf16(pa1, v1, oacc[nb], 0, 0, 0);
    }
  }

#pragma unroll
  for (int nb = 0; nb < 4; ++nb) {
#pragma unroll
    for (int r = 0; r < 4; ++r) {
      const int row = lg * 4 + r;
      const int col = nb * 16 + lr;
      O[((size_t)(b * kT + q0 + wv * 16 + row)) * kD + h * kHD + col] = f2bf(oacc[nb][r] / l_[r]);
    }
  }
}

// ---------- positional encoding add (f32 + bf16 copy) ----------
__global__ __launch_bounds__(256) void posenc_kernel(float* __restrict__ X, ushort* __restrict__ Xb)
{
  const int bt = blockIdx.x;
  const int t = bt & (kT - 1);
  float* row = X + (size_t)bt * kD;
  ushort* rb = Xb + (size_t)bt * kD;
#pragma unroll
  for (int p = 0; p < 2; ++p) {
    const int d = threadIdx.x + p * 256;
    const int j = d >> 1;
    const float inv = expf(-(float)j * 0.03597789207803197f);  // ln(10000)/256
    const float ang = (float)t * inv;
    const float pe = (d & 1) ? cosf(ang) : sinf(ang);
    const float v = row[d] + pe;
    row[d] = v;
    rb[d] = f2bf(v);
  }
}

// ---------- fused avgpool + im2col (bf16 out) ----------
__global__ void im2col_pool_kernel(const float* __restrict__ X, ushort* __restrict__ X5,
                                   int Tt, int n4)
{
  const int idx = blockIdx.x * 256 + threadIdx.x;
  if (idx >= n4) return;
  const int ci4 = idx & 127;
  int r = idx >> 7;
  const int tap = r % 5; r /= 5;
  const int t = r % Tt;
  const int b = r / Tt;
  const int ts = t + tap - 2;
  u16x4_t o = (u16x4_t){0, 0, 0, 0};
  if (ts >= 0 && ts < Tt) {
    const float* p = X + ((size_t)(b * 2 * Tt + 2 * ts)) * kD + ci4 * 4;
    const float4 x0 = *(const float4*)p;
    const float4 x1 = *(const float4*)(p + kD);
    o[0] = f2bf(0.5f * (x0.x + x1.x)); o[1] = f2bf(0.5f * (x0.y + x1.y));
    o[2] = f2bf(0.5f * (x0.z + x1.z)); o[3] = f2bf(0.5f * (x0.w + x1.w));
  }
  *(u16x4_t*)&X5[((size_t)(b * Tt + t)) * 2560 + tap * kD + ci4 * 4] = o;
}

// conv weight transpose -> bf16: Wt[co][tap*512+ci] = w[co][ci][tap]
__global__ void convw_t_kernel(const float* __restrict__ w, ushort* __restrict__ Wt)
{
  const int idx = blockIdx.x * 256 + threadIdx.x;
  if (idx >= 512 * 512 * 5) return;
  const int ci = idx & 511;
  int r = idx >> 9;
  const int tap = r % 5;
  const int co = r / 5;
  Wt[(size_t)co * 2560 + tap * 512 + ci] = f2bf(w[(size_t)co * 2560 + ci * 5 + tap]);
}

extern "C" void kernel_launch(void* const* d_in, const int* in_sizes, int n_in,
                              void* d_out, int out_size, void* d_ws, size_t ws_size,
                              hipStream_t stream)
{
  (void)in_sizes; (void)n_in; (void)out_size;
  const float* poses  = (const float*)d_in[0];
  const float* pose_w = (const float*)d_in[1];
  const float* pose_b = (const float*)d_in[2];
  const float* in_w   = (const float*)d_in[3];
  const float* in_b   = (const float*)d_in[4];
  const float* out_w  = (const float*)d_in[5];
  const float* out_b  = (const float*)d_in[6];
  const float* ln1_g  = (const float*)d_in[7];
  const float* ln1_b  = (const float*)d_in[8];
  const float* ffn_w1 = (const float*)d_in[9];
  const float* ffn_b1 = (const float*)d_in[10];
  const float* ffn_w2 = (const float*)d_in[11];
  const float* ffn_b2 = (const float*)d_in[12];
  const float* ln2_g  = (const float*)d_in[13];
  const float* ln2_b  = (const float*)d_in[14];
  const float* tcn1_w = (const float*)d_in[15];
  const float* tcn1_b = (const float*)d_in[16];
  const float* tcn2_w = (const float*)d_in[17];
  const float* tcn2_b = (const float*)d_in[18];
  const float* fc1_w  = (const float*)d_in[19];
  const float* fc1_b  = (const float*)d_in[20];
  const float* fc2_w  = (const float*)d_in[21];
  const float* fc2_b  = (const float*)d_in[22];

  // ---- workspace layout (byte offsets) ----
  char* base = (char*)d_ws;
  float*  A    = (float*)(base);
  float*  Y    = (float*)(base + 8388608);
  float*  P    = (float*)(base + 16777216);
  ushort* Abf  = (ushort*)(base + 25165824);
  ushort* QKV  = (ushort*)(base + 29360128);   // 6M ushort
  ushort* Ybf  = QKV;                          // lifetime-disjoint alias
  ushort* X5   = QKV;                          // head phase
  ushort* MID  = (ushort*)(base + 41943040);   // 8M ushort
  ushort* ATTb = MID;                          // lifetime-disjoint alias
  ushort* CW   = MID;                          // head phase
  ushort* Wbf  = (ushort*)(base + 58720256);

  // per-layer weight element counts
  const size_t nWq = (size_t)3 * kD * kD;      // 786432
  const size_t nWo = (size_t)kD * kD;          // 262144
  const size_t nW1 = (size_t)kFF * kD;         // 1048576
  const size_t nW2 = (size_t)kD * kFF;         // 1048576
  const size_t nWl = nWq + nWo + nW1 + nW2;    // 3145728
  const bool fullW = ws_size >= (size_t)58720256 + nWl * 8 * 2;

  const int M = kB * kT;  // 4096
  dim3 blk(256);
  auto cvt = [&](const float* s, ushort* d, size_t n) {
    cvt_kernel<<<(int)((n / 8 + 255) / 256), blk, 0, stream>>>(s, d, (int)(n / 8));
  };

  if (fullW) {   // one-time per launch: convert all transformer weights
    cvt(in_w,   Wbf,                        nWq * 8);
    cvt(out_w,  Wbf + nWq * 8,              nWo * 8);
    cvt(ffn_w1, Wbf + nWq * 8 + nWo * 8,    nW1 * 8);
    cvt(ffn_w2, Wbf + (nWq + nWo + nW1) * 8, nW2 * 8);
  }

  // embed: A = poses @ pose_w.T + pose_b ; += posenc (writes A + Abf)
  gemm_kernel<<<dim3(kD / GBN, M / GBM), blk, 0, stream>>>(poses, pose_w, pose_b, nullptr, A, M, kD, kIn, 0);
  posenc_kernel<<<M, blk, 0, stream>>>(A, Abf);

  for (int l = 0; l < 8; ++l) {
    const ushort *Wq, *Wo, *W1, *W2;
    if (fullW) {
      Wq = Wbf + (size_t)l * nWq;
      Wo = Wbf + nWq * 8 + (size_t)l * nWo;
      W1 = Wbf + nWq * 8 + nWo * 8 + (size_t)l * nW1;
      W2 = Wbf + (nWq + nWo + nW1) * 8 + (size_t)l * nW2;
    } else {   // rotate: convert this layer's weights into Wbf
      cvt(in_w   + (size_t)l * nWq, Wbf, nWq);
      cvt(out_w  + (size_t)l * nWo, Wbf + nWq, nWo);
      cvt(ffn_w1 + (size_t)l * nW1, Wbf + nWq + nWo, nW1);
      cvt(ffn_w2 + (size_t)l * nW2, Wbf + nWq + nWo + nW1, nW2);
      Wq = Wbf; Wo = Wbf + nWq; W1 = Wbf + nWq + nWo; W2 = Wbf + nWq + nWo + nW1;
    }

    // qkv (bf16 out only)
    bgemm_kernel<4, 4><<<dim3(3 * kD / 128, M / 128), blk, 0, stream>>>(
        Abf, Wq, in_b + (size_t)l * 3 * kD, nullptr, nullptr, QKV, M, 3 * kD, kD, 0);
    // attention (bf16 in/out)
    attn_mfma_kernel<<<dim3(kT / 64, kH, kB), blk, 0, stream>>>(QKV, ATTb);
    // out-proj: Y = ATTb @ Wo + b + A (f32 out)
    bgemm_kernel<2, 4><<<dim3(kD / 128, M / 64), blk, 0, stream>>>(
        ATTb, Wo, out_b + (size_t)l * kD, A, Y, nullptr, M, kD, kD, 0);
    ln_kernel<<<M, blk, 0, stream>>>(Y, Ybf, ln1_g + (size_t)l * kD, ln1_b + (size_t)l * kD,
                                     nullptr, nullptr);
    // ffn1: MID = relu(Ybf @ W1 + b)  (bf16 out only)
    bgemm_kernel<4, 4><<<dim3(kFF / 128, M / 128), blk, 0, stream>>>(
        Ybf, W1, ffn_b1 + (size_t)l * kFF, nullptr, nullptr, MID, M, kFF, kD, 1);
    // ffn2: A = MID @ W2 + b + Y (f32 out)
    bgemm_kernel<2, 4><<<dim3(kD / 128, M / 64), blk, 0, stream>>>(
        MID, W2, ffn_b2 + (size_t)l * kD, Y, A, nullptr, M, kD, kFF, 0);
    // ln2, fused with skip-stream: add P after LN (l=3,5,7), snapshot P (l=1,3,5)
    {
      const float* padd = (l == 3 || l == 5 || l == 7) ? P : nullptr;
      float* pout = (l == 1 || l == 3 || l == 5) ? P : nullptr;
      ln_kernel<<<M, blk, 0, stream>>>(A, Abf, ln2_g + (size_t)l * kD, ln2_b + (size_t)l * kD,
                                       padd, pout);
    }
  }

  // head: pool+conv1 -> pool+conv2 -> fc1 -> fc2
  {
    const int T1 = kT / 2;   // 512
    const int T2 = kT / 4;   // 256
    convw_t_kernel<<<(512 * 512 * 5 + 255) / 256, blk, 0, stream>>>(tcn1_w, CW);
    const int n4a = kB * T1 * 5 * (kD / 4);
    im2col_pool_kernel<<<(n4a + 255) / 256, blk, 0, stream>>>(A, X5, T1, n4a);
    bgemm_kernel<2, 2><<<dim3(kD / 64, kB * T1 / 64), blk, 0, stream>>>(
        X5, CW, tcn1_b, nullptr, Y, nullptr, kB * T1, kD, 2560, 0);
    convw_t_kernel<<<(512 * 512 * 5 + 255) / 256, blk, 0, stream>>>(tcn2_w, CW);
    const int n4b = kB * T2 * 5 * (kD / 4);
    im2col_pool_kernel<<<(n4b + 255) / 256, blk, 0, stream>>>(Y, X5, T2, n4b);
    bgemm_kernel<2, 2><<<dim3(kD / 64, kB * T2 / 64), blk, 0, stream>>>(
        X5, CW, tcn2_b, nullptr, A, nullptr, kB * T2, kD, 2560, 0);
    const int Mh = kB * T2;  // 1024
    gemm_kernel<<<dim3(128 / GBN, Mh / GBM), blk, 0, stream>>>(A, fc1_w, fc1_b, nullptr, Y, Mh, 128, kD, 0);
    gemm_kernel<<<dim3((kNCLS + GBN - 1) / GBN, Mh / GBM), blk, 0, stream>>>(
        Y, fc2_w, fc2_b, nullptr, (float*)d_out, Mh, kNCLS, 128, 0);
  }
}